// Round 1
// baseline (337.108 us; speedup 1.0000x reference)
//
#include <hip/hip_runtime.h>
#include <math.h>

#define QN 256
#define KN 512
#define DN 256
#define SCALE 0.0625f  // 1/sqrt(256)

__device__ __forceinline__ float sigf(float x){ return 1.0f/(1.0f+expf(-x)); }

// all-threads-call, blockDim.x == 256
__device__ __forceinline__ float block_reduce_sum256(float v, float* red){
  int t = threadIdx.x;
  red[t] = v; __syncthreads();
  #pragma unroll
  for (int s = 128; s > 0; s >>= 1){
    if (t < s) red[t] += red[t+s];
    __syncthreads();
  }
  float r = red[0];
  __syncthreads();
  return r;
}

// K1: q_glob_enc = mean(q_enc, axis=0); tmp_glob = qge@W_glob+b_glob; g1 = qge@W_gv0+b_gv0
__global__ void k1_prep(const float* __restrict__ q_enc,
                        const float* __restrict__ W_glob, const float* __restrict__ b_glob,
                        const float* __restrict__ W_gv0, const float* __restrict__ b_gv0,
                        float* __restrict__ tmp_glob, float* __restrict__ g1){
  __shared__ float sm[DN];
  int t = threadIdx.x;
  float acc = 0.f;
  for (int q = 0; q < QN; ++q) acc += q_enc[q*DN + t];
  sm[t] = acc * (1.0f/QN);
  __syncthreads();
  float a0 = b_glob[t], a1 = b_gv0[t];
  for (int j = 0; j < DN; ++j){
    float s = sm[j];
    a0 = fmaf(s, W_glob[j*DN + t], a0);
    a1 = fmaf(s, W_gv0[j*DN + t], a1);
  }
  tmp_glob[t] = a0; g1[t] = a1;
}

// K2 (block per k row): k_s, k_1, k_enc2; also c[k]=k_enc2[k]·Wg1, gl2[k]=k_enc2[k]·Wg2
__global__ void k2_kenc2(const float* __restrict__ k_enc,
                         const float* __restrict__ W_gv1, const float* __restrict__ b_gv1,
                         const float* __restrict__ tmp_glob, const float* __restrict__ g1,
                         const float* __restrict__ W_locgate,
                         float* __restrict__ k_enc2, float* __restrict__ cvec,
                         float* __restrict__ gl2){
  __shared__ float krow[DN];
  __shared__ float red[DN];
  int k = blockIdx.x, t = threadIdx.x;
  float kv = k_enc[k*DN + t];
  krow[t] = kv;
  float dot = block_reduce_sum256(kv * tmp_glob[t], red);
  float ks = sigf(dot * SCALE);
  float acc = b_gv1[t];
  for (int j = 0; j < DN; ++j) acc = fmaf(krow[j], W_gv1[j*DN + t], acc);
  float v = (1.f - ks)*acc + ks*g1[t];
  k_enc2[k*DN + t] = v;
  float c  = block_reduce_sum256(v * W_locgate[t],      red);
  float g2 = block_reduce_sum256(v * W_locgate[DN + t], red);
  if (t == 0){ cvec[k] = c; gl2[k] = g2; }
}

// K3 (block per q row): q_glob = q_enc@W_gq+b; q_loc = q_enc@W_lq+b
__global__ void k3_qproj(const float* __restrict__ q_enc,
                         const float* __restrict__ W_gq, const float* __restrict__ b_gq,
                         const float* __restrict__ W_lq, const float* __restrict__ b_lq,
                         float* __restrict__ q_glob, float* __restrict__ q_loc){
  __shared__ float qrow[DN];
  int q = blockIdx.x, t = threadIdx.x;
  qrow[t] = q_enc[q*DN + t];
  __syncthreads();
  float a = b_gq[t], b = b_lq[t];
  for (int j = 0; j < DN; ++j){
    float s = qrow[j];
    a = fmaf(s, W_gq[j*DN + t], a);
    b = fmaf(s, W_lq[j*DN + t], b);
  }
  q_glob[q*DN + t] = a; q_loc[q*DN + t] = b;
}

// KB (big pass 1): one wave per (q,k). qk_r[q,k]=q_glob[q]·rel_k[q,k]; qnk_r likewise with q_loc
__global__ void kb_relk(const float* __restrict__ rel_k,
                        const float* __restrict__ q_glob, const float* __restrict__ q_loc,
                        float* __restrict__ qk_r, float* __restrict__ qnk_r){
  int w = blockIdx.x*4 + (threadIdx.x >> 6);
  int lane = threadIdx.x & 63;
  int q = w >> 9, k = w & 511;
  const float4* rk = (const float4*)(rel_k + (size_t)(q*KN + k)*DN);
  float4 x = rk[lane];
  float4 a = ((const float4*)(q_glob + q*DN))[lane];
  float4 b = ((const float4*)(q_loc  + q*DN))[lane];
  float p1 = x.x*a.x + x.y*a.y + x.z*a.z + x.w*a.w;
  float p2 = x.x*b.x + x.y*b.y + x.z*b.z + x.w*b.w;
  #pragma unroll
  for (int off = 32; off; off >>= 1){ p1 += __shfl_down(p1, off); p2 += __shfl_down(p2, off); }
  if (lane == 0){ qk_r[q*KN + k] = p1; qnk_r[q*KN + k] = p2; }
}

// KC1 (block per q): logits vs k_enc2^T fused with rel terms -> glob_attn g, e=exp(loc_attn), ec=e*c
__global__ void kc1_attn(const float* __restrict__ q_glob, const float* __restrict__ q_loc,
                         const float* __restrict__ k_enc2,
                         const float* __restrict__ qk_r, const float* __restrict__ qnk_r,
                         const float* __restrict__ cvec,
                         float* __restrict__ g, float* __restrict__ e, float* __restrict__ ec){
  int q = blockIdx.x, t = threadIdx.x, w = t >> 6, lane = t & 63;
  __shared__ float qg[DN], ql[DN], exs[KN], red[DN];
  qg[t] = q_glob[q*DN + t];
  ql[t] = q_loc[q*DN + t];
  __syncthreads();
  float4 a4 = ((const float4*)qg)[lane];
  float4 b4 = ((const float4*)ql)[lane];
  for (int k = w; k < KN; k += 4){
    float4 x = ((const float4*)(k_enc2 + k*DN))[lane];
    float p1 = x.x*a4.x + x.y*a4.y + x.z*a4.z + x.w*a4.w;
    float p2 = x.x*b4.x + x.y*b4.y + x.z*b4.z + x.w*b4.w;
    #pragma unroll
    for (int off = 32; off; off >>= 1){ p1 += __shfl_down(p1, off); p2 += __shfl_down(p2, off); }
    if (lane == 0){
      float t1 = tanhf((p1 + qk_r[q*KN + k]) * SCALE);
      exs[k] = expf(t1);
      float ev = expf(tanhf((p2 + qnk_r[q*KN + k]) * SCALE));
      e[q*KN + k]  = ev;
      ec[q*KN + k] = ev * cvec[k];
    }
  }
  __syncthreads();
  float v = exs[t] + exs[t + 256];
  float tot = block_reduce_sum256(v, red);
  float inv = 1.0f / tot;
  g[q*KN + t]       = exs[t] * inv;
  g[q*KN + t + 256] = exs[t + 256] * inv;
}

// KC2 (block per q): s[q,i]=Σ M[i,j]e[q,j]; numg=Σ M[i,j]ec[q,j] -> wv=g*lg/s, v2=g*(1-lg)
__global__ void kc2_sw(const int* __restrict__ k_adj,
                       const float* __restrict__ e, const float* __restrict__ ec,
                       const float* __restrict__ g, const float* __restrict__ gl2,
                       const float* __restrict__ b_locgate,
                       float* __restrict__ wv, float* __restrict__ v2){
  int q = blockIdx.x, t = threadIdx.x, w = t >> 6, lane = t & 63;
  __shared__ float e_s[KN], ec_s[KN], g_s[KN];
  e_s[t] = e[q*KN + t];   e_s[t+256] = e[q*KN + t + 256];
  ec_s[t] = ec[q*KN + t]; ec_s[t+256] = ec[q*KN + t + 256];
  g_s[t] = g[q*KN + t];   g_s[t+256] = g[q*KN + t + 256];
  __syncthreads();
  float blg = b_locgate[0];
  for (int i = w; i < KN; i += 4){
    float as = 0.f, an = 0.f;
    #pragma unroll
    for (int tt = 0; tt < 8; ++tt){
      int j = tt*64 + lane;
      float m = (k_adj[i*KN + j] != 0) ? 1.0f : 0.0f;
      as = fmaf(m, e_s[j], as);
      an = fmaf(m, ec_s[j], an);
    }
    #pragma unroll
    for (int off = 32; off; off >>= 1){ as += __shfl_down(as, off); an += __shfl_down(an, off); }
    if (lane == 0){
      float lg = sigf(an/as + gl2[i] + blg);
      wv[q*KN + i] = g_s[i]*lg/as;
      v2[q*KN + i] = g_s[i]*(1.f - lg);
    }
  }
}

// KC3 (block per q): u[q,j]=Σ_i wv[q,i]M[i,j]; coef = u*e + v2
__global__ void kc3_coef(const int* __restrict__ k_adj,
                         const float* __restrict__ wv, const float* __restrict__ e,
                         const float* __restrict__ v2, float* __restrict__ coef){
  int q = blockIdx.x, t = threadIdx.x;
  __shared__ float w_s[KN];
  w_s[t] = wv[q*KN + t]; w_s[t+256] = wv[q*KN + t + 256];
  __syncthreads();
  float a0 = 0.f, a1 = 0.f;
  for (int i = 0; i < KN; ++i){
    float wi = w_s[i];
    a0 = fmaf((k_adj[i*KN + t]       != 0) ? 1.f : 0.f, wi, a0);
    a1 = fmaf((k_adj[i*KN + t + 256] != 0) ? 1.f : 0.f, wi, a1);
  }
  coef[q*KN + t]       = a0*e[q*KN + t]       + v2[q*KN + t];
  coef[q*KN + t + 256] = a1*e[q*KN + t + 256] + v2[q*KN + t + 256];
}

// KC4 (block per q): k_matmul = coef @ k_enc2
__global__ void kc4_kmat(const float* __restrict__ coef, const float* __restrict__ k_enc2,
                         float* __restrict__ k_matmul){
  int q = blockIdx.x, t = threadIdx.x;
  __shared__ float c_s[KN];
  c_s[t] = coef[q*KN + t]; c_s[t+256] = coef[q*KN + t + 256];
  __syncthreads();
  float acc = 0.f;
  for (int k = 0; k < KN; ++k) acc = fmaf(c_s[k], k_enc2[k*DN + t], acc);
  k_matmul[q*DN + t] = acc;
}

// KD (big pass 2): k_r_matmul partials. grid (8 k-splits, 256 q). wave-per-k-slice, float4 over d.
__global__ void kd_relv(const float* __restrict__ rel_v, const float* __restrict__ g,
                        float* __restrict__ part){
  int s = blockIdx.x, q = blockIdx.y;
  int t = threadIdx.x, w = t >> 6, lane = t & 63;
  __shared__ float4 lacc[4][64];
  float4 acc = make_float4(0.f, 0.f, 0.f, 0.f);
  int kbase = s*64 + w*16;
  for (int tt = 0; tt < 16; ++tt){
    int k = kbase + tt;
    float a = g[q*KN + k];
    float4 x = ((const float4*)(rel_v + (size_t)(q*KN + k)*DN))[lane];
    acc.x = fmaf(a, x.x, acc.x); acc.y = fmaf(a, x.y, acc.y);
    acc.z = fmaf(a, x.z, acc.z); acc.w = fmaf(a, x.w, acc.w);
  }
  lacc[w][lane] = acc;
  __syncthreads();
  if (t < 64){
    float4 r = lacc[0][t], b = lacc[1][t], c = lacc[2][t], d4 = lacc[3][t];
    r.x += b.x + c.x + d4.x; r.y += b.y + c.y + d4.y;
    r.z += b.z + c.z + d4.z; r.w += b.w + c.w + d4.w;
    ((float4*)(part + (size_t)(s*QN + q)*DN))[t] = r;
  }
}

// KE (block per q): q_enc_new = k_matmul + Σ part; gate; h
__global__ void ke_out(const float* __restrict__ part, const float* __restrict__ k_matmul,
                       const float* __restrict__ q_enc, const float* __restrict__ W_gate,
                       const float* __restrict__ b_gate, float* __restrict__ out){
  int q = blockIdx.x, t = threadIdx.x;
  __shared__ float red[DN];
  float qen = k_matmul[q*DN + t];
  #pragma unroll
  for (int s = 0; s < 8; ++s) qen += part[(size_t)(s*QN + q)*DN + t];
  float qe = q_enc[q*DN + t];
  float dot = block_reduce_sum256(qen*W_gate[t] + qe*W_gate[DN + t], red);
  float gate = sigf(dot + b_gate[0]);
  out[q*DN + t] = gate*qen + (1.f - gate)*qe;
}

extern "C" void kernel_launch(void* const* d_in, const int* in_sizes, int n_in,
                              void* d_out, int out_size, void* d_ws, size_t ws_size,
                              hipStream_t stream){
  const float* q_enc     = (const float*)d_in[0];
  const float* k_enc     = (const float*)d_in[1];
  const float* rel_k     = (const float*)d_in[2];
  const float* rel_v     = (const float*)d_in[3];
  const int*   k_adj     = (const int*)  d_in[4];
  const float* W_glob    = (const float*)d_in[5];
  const float* b_glob    = (const float*)d_in[6];
  const float* W_gv0     = (const float*)d_in[7];
  const float* b_gv0     = (const float*)d_in[8];
  const float* W_gv1     = (const float*)d_in[9];
  const float* b_gv1     = (const float*)d_in[10];
  const float* W_gq      = (const float*)d_in[11];
  const float* b_gq      = (const float*)d_in[12];
  const float* W_lq      = (const float*)d_in[13];
  const float* b_lq      = (const float*)d_in[14];
  const float* W_locgate = (const float*)d_in[15];
  const float* b_locgate = (const float*)d_in[16];
  const float* W_gate    = (const float*)d_in[17];
  const float* b_gate    = (const float*)d_in[18];
  float* out = (float*)d_out;

  float* ws = (float*)d_ws;
  float* tmp_glob = ws;                    // 256
  float* g1       = tmp_glob + 256;        // 256
  float* k_enc2   = g1 + 256;              // 131072
  float* cvec     = k_enc2 + 131072;       // 512
  float* gl2      = cvec + 512;            // 512
  float* q_glob   = gl2 + 512;             // 65536
  float* q_loc    = q_glob + 65536;        // 65536
  float* qk_r     = q_loc + 65536;         // 131072
  float* qnk_r    = qk_r + 131072;         // 131072
  float* gat      = qnk_r + 131072;        // 131072
  float* ev       = gat + 131072;          // 131072
  float* ecv      = ev + 131072;           // 131072
  float* wv       = ecv + 131072;          // 131072
  float* v2       = wv + 131072;           // 131072
  float* coef     = v2 + 131072;           // 131072
  float* k_matmul = coef + 131072;         // 65536
  float* part     = k_matmul + 65536;      // 8*65536 = 524288

  k1_prep<<<1, 256, 0, stream>>>(q_enc, W_glob, b_glob, W_gv0, b_gv0, tmp_glob, g1);
  k2_kenc2<<<512, 256, 0, stream>>>(k_enc, W_gv1, b_gv1, tmp_glob, g1, W_locgate,
                                    k_enc2, cvec, gl2);
  k3_qproj<<<256, 256, 0, stream>>>(q_enc, W_gq, b_gq, W_lq, b_lq, q_glob, q_loc);
  kb_relk<<<32768, 256, 0, stream>>>(rel_k, q_glob, q_loc, qk_r, qnk_r);
  kc1_attn<<<256, 256, 0, stream>>>(q_glob, q_loc, k_enc2, qk_r, qnk_r, cvec, gat, ev, ecv);
  kc2_sw<<<256, 256, 0, stream>>>(k_adj, ev, ecv, gat, gl2, b_locgate, wv, v2);
  kc3_coef<<<256, 256, 0, stream>>>(k_adj, wv, ev, v2, coef);
  kc4_kmat<<<256, 256, 0, stream>>>(coef, k_enc2, k_matmul);
  kd_relv<<<dim3(8, 256), 256, 0, stream>>>(rel_v, gat, part);
  ke_out<<<256, 256, 0, stream>>>(part, k_matmul, q_enc, W_gate, b_gate, out);
}

// Round 2
// 180.596 us; speedup vs baseline: 1.8666x; 1.8666x over previous
//
#include <hip/hip_runtime.h>
#include <math.h>

#define QN 256
#define KN 512
#define DN 256
#define SCALE 0.0625f  // 1/sqrt(256)

__device__ __forceinline__ float sigf(float x){ return 1.0f/(1.0f+expf(-x)); }

// all-threads-call, blockDim.x == 256
__device__ __forceinline__ float block_reduce_sum256(float v, float* red){
  int t = threadIdx.x;
  red[t] = v; __syncthreads();
  #pragma unroll
  for (int s = 128; s > 0; s >>= 1){
    if (t < s) red[t] += red[t+s];
    __syncthreads();
  }
  float r = red[0];
  __syncthreads();
  return r;
}

// K1: q_glob_enc = mean(q_enc, axis=0); tmp_glob = qge@W_glob+b_glob; g1 = qge@W_gv0+b_gv0
__global__ void k1_prep(const float* __restrict__ q_enc,
                        const float* __restrict__ W_glob, const float* __restrict__ b_glob,
                        const float* __restrict__ W_gv0, const float* __restrict__ b_gv0,
                        float* __restrict__ tmp_glob, float* __restrict__ g1){
  __shared__ float sm[DN];
  int t = threadIdx.x;
  float acc = 0.f;
  for (int q = 0; q < QN; ++q) acc += q_enc[q*DN + t];
  sm[t] = acc * (1.0f/QN);
  __syncthreads();
  float a0 = b_glob[t], a1 = b_gv0[t];
  for (int j = 0; j < DN; ++j){
    float s = sm[j];
    a0 = fmaf(s, W_glob[j*DN + t], a0);
    a1 = fmaf(s, W_gv0[j*DN + t], a1);
  }
  tmp_glob[t] = a0; g1[t] = a1;
}

// K2 (block per k row): k_s, k_1, k_enc2; also c[k]=k_enc2[k]·Wg1, gl2[k]=k_enc2[k]·Wg2
__global__ void k2_kenc2(const float* __restrict__ k_enc,
                         const float* __restrict__ W_gv1, const float* __restrict__ b_gv1,
                         const float* __restrict__ tmp_glob, const float* __restrict__ g1,
                         const float* __restrict__ W_locgate,
                         float* __restrict__ k_enc2, float* __restrict__ cvec,
                         float* __restrict__ gl2){
  __shared__ float krow[DN];
  __shared__ float red[DN];
  int k = blockIdx.x, t = threadIdx.x;
  float kv = k_enc[k*DN + t];
  krow[t] = kv;
  float dot = block_reduce_sum256(kv * tmp_glob[t], red);
  float ks = sigf(dot * SCALE);
  float acc = b_gv1[t];
  for (int j = 0; j < DN; ++j) acc = fmaf(krow[j], W_gv1[j*DN + t], acc);
  float v = (1.f - ks)*acc + ks*g1[t];
  k_enc2[k*DN + t] = v;
  float c  = block_reduce_sum256(v * W_locgate[t],      red);
  float g2 = block_reduce_sum256(v * W_locgate[DN + t], red);
  if (t == 0){ cvec[k] = c; gl2[k] = g2; }
}

// K3 (block per q row): q_glob = q_enc@W_gq+b; q_loc = q_enc@W_lq+b
__global__ void k3_qproj(const float* __restrict__ q_enc,
                         const float* __restrict__ W_gq, const float* __restrict__ b_gq,
                         const float* __restrict__ W_lq, const float* __restrict__ b_lq,
                         float* __restrict__ q_glob, float* __restrict__ q_loc){
  __shared__ float qrow[DN];
  int q = blockIdx.x, t = threadIdx.x;
  qrow[t] = q_enc[q*DN + t];
  __syncthreads();
  float a = b_gq[t], b = b_lq[t];
  for (int j = 0; j < DN; ++j){
    float s = qrow[j];
    a = fmaf(s, W_gq[j*DN + t], a);
    b = fmaf(s, W_lq[j*DN + t], b);
  }
  q_glob[q*DN + t] = a; q_loc[q*DN + t] = b;
}

// KB (big pass 1): one wave per (q,k). qk_r[q,k]=q_glob[q]·rel_k[q,k]; qnk_r with q_loc
__global__ void kb_relk(const float* __restrict__ rel_k,
                        const float* __restrict__ q_glob, const float* __restrict__ q_loc,
                        float* __restrict__ qk_r, float* __restrict__ qnk_r){
  int w = blockIdx.x*4 + (threadIdx.x >> 6);
  int lane = threadIdx.x & 63;
  int q = w >> 9, k = w & 511;
  const float4* rk = (const float4*)(rel_k + (size_t)(q*KN + k)*DN);
  float4 x = rk[lane];
  float4 a = ((const float4*)(q_glob + q*DN))[lane];
  float4 b = ((const float4*)(q_loc  + q*DN))[lane];
  float p1 = x.x*a.x + x.y*a.y + x.z*a.z + x.w*a.w;
  float p2 = x.x*b.x + x.y*b.y + x.z*b.z + x.w*b.w;
  #pragma unroll
  for (int off = 32; off; off >>= 1){ p1 += __shfl_down(p1, off); p2 += __shfl_down(p2, off); }
  if (lane == 0){ qk_r[q*KN + k] = p1; qnk_r[q*KN + k] = p2; }
}

// kcL: dual GEMM {q_glob,q_loc} @ k_enc2^T, epilogue: exs=exp(tanh((p1+qk_r)s)) (into qk_r),
//      ev=exp(tanh((p2+qnk_r)s)), ec=ev*c[k].  grid (16,8), 256 thr, 32q x 32k tile.
__global__ __launch_bounds__(256) void kcL(const float* __restrict__ qg, const float* __restrict__ ql,
                                           const float* __restrict__ ke2, const float* __restrict__ cvec,
                                           float* __restrict__ qkr, const float* __restrict__ qnkr,
                                           float* __restrict__ ev, float* __restrict__ ec){
  __shared__ float sA[64][34], sL[64][34], sB[64][34];
  int t = threadIdx.x;
  int q0 = blockIdx.y*32, k0 = blockIdx.x*32;
  int tq = t & 15, tk = t >> 4;
  float a1[2][2] = {{0.f,0.f},{0.f,0.f}}, a2[2][2] = {{0.f,0.f},{0.f,0.f}};
  for (int d0 = 0; d0 < DN; d0 += 64){
    #pragma unroll
    for (int r = 0; r < 2; ++r){
      int f = t + 256*r; int row = f >> 4; int c4 = (f & 15)*4;
      float4 va = *(const float4*)(qg  + (size_t)(q0+row)*DN + d0 + c4);
      float4 vl = *(const float4*)(ql  + (size_t)(q0+row)*DN + d0 + c4);
      float4 vb = *(const float4*)(ke2 + (size_t)(k0+row)*DN + d0 + c4);
      sA[c4+0][row]=va.x; sA[c4+1][row]=va.y; sA[c4+2][row]=va.z; sA[c4+3][row]=va.w;
      sL[c4+0][row]=vl.x; sL[c4+1][row]=vl.y; sL[c4+2][row]=vl.z; sL[c4+3][row]=vl.w;
      sB[c4+0][row]=vb.x; sB[c4+1][row]=vb.y; sB[c4+2][row]=vb.z; sB[c4+3][row]=vb.w;
    }
    __syncthreads();
    #pragma unroll 8
    for (int d = 0; d < 64; ++d){
      float2 av = *(const float2*)&sA[d][tq*2];
      float2 lv = *(const float2*)&sL[d][tq*2];
      float2 bv = *(const float2*)&sB[d][tk*2];
      a1[0][0] = fmaf(av.x, bv.x, a1[0][0]); a1[0][1] = fmaf(av.x, bv.y, a1[0][1]);
      a1[1][0] = fmaf(av.y, bv.x, a1[1][0]); a1[1][1] = fmaf(av.y, bv.y, a1[1][1]);
      a2[0][0] = fmaf(lv.x, bv.x, a2[0][0]); a2[0][1] = fmaf(lv.x, bv.y, a2[0][1]);
      a2[1][0] = fmaf(lv.y, bv.x, a2[1][0]); a2[1][1] = fmaf(lv.y, bv.y, a2[1][1]);
    }
    __syncthreads();
  }
  #pragma unroll
  for (int qq = 0; qq < 2; ++qq)
    #pragma unroll
    for (int kk = 0; kk < 2; ++kk){
      int q = q0 + tq*2 + qq, k = k0 + tk*2 + kk;
      size_t idx = (size_t)q*KN + k;
      float p1 = a1[qq][kk] + qkr[idx];
      qkr[idx] = expf(tanhf(p1*SCALE));
      float p2 = a2[qq][kk] + qnkr[idx];
      float evv = expf(tanhf(p2*SCALE));
      ev[idx] = evv; ec[idx] = evv*cvec[k];
    }
}

// kcS: row-normalize exs -> glob_attn g. block per q.
__global__ void kcS(const float* __restrict__ exs, float* __restrict__ g){
  __shared__ float red[256];
  int q = blockIdx.x, t = threadIdx.x;
  float a = exs[q*KN + t], b = exs[q*KN + t + 256];
  float tot = block_reduce_sum256(a + b, red);
  float inv = 1.0f / tot;
  g[q*KN + t] = a*inv; g[q*KN + t + 256] = b*inv;
}

// kcA: dual GEMM {e,ec} @ M^T over j; epilogue -> wv, v2. grid (16,8), 32q x 32i tile.
__global__ __launch_bounds__(256) void kcA(const int* __restrict__ kadj,
                                           const float* __restrict__ e, const float* __restrict__ ec,
                                           const float* __restrict__ g, const float* __restrict__ gl2,
                                           const float* __restrict__ blg_p,
                                           float* __restrict__ wv, float* __restrict__ v2){
  __shared__ float sE[64][34], sC[64][34], sM[64][34];
  int t = threadIdx.x;
  int q0 = blockIdx.y*32, i0 = blockIdx.x*32;
  int tq = t & 15, ti = t >> 4;
  float as[2][2] = {{0.f,0.f},{0.f,0.f}}, an[2][2] = {{0.f,0.f},{0.f,0.f}};
  for (int j0 = 0; j0 < KN; j0 += 64){
    #pragma unroll
    for (int r = 0; r < 2; ++r){
      int f = t + 256*r; int row = f >> 4; int c4 = (f & 15)*4;
      float4 vE = *(const float4*)(e  + (size_t)(q0+row)*KN + j0 + c4);
      float4 vC = *(const float4*)(ec + (size_t)(q0+row)*KN + j0 + c4);
      int4  vM = *(const int4*)(kadj + (size_t)(i0+row)*KN + j0 + c4);
      sE[c4+0][row]=vE.x; sE[c4+1][row]=vE.y; sE[c4+2][row]=vE.z; sE[c4+3][row]=vE.w;
      sC[c4+0][row]=vC.x; sC[c4+1][row]=vC.y; sC[c4+2][row]=vC.z; sC[c4+3][row]=vC.w;
      sM[c4+0][row]=vM.x?1.f:0.f; sM[c4+1][row]=vM.y?1.f:0.f;
      sM[c4+2][row]=vM.z?1.f:0.f; sM[c4+3][row]=vM.w?1.f:0.f;
    }
    __syncthreads();
    #pragma unroll 8
    for (int j = 0; j < 64; ++j){
      float2 ev2 = *(const float2*)&sE[j][tq*2];
      float2 cv2 = *(const float2*)&sC[j][tq*2];
      float2 mv2 = *(const float2*)&sM[j][ti*2];
      as[0][0]=fmaf(ev2.x,mv2.x,as[0][0]); as[0][1]=fmaf(ev2.x,mv2.y,as[0][1]);
      as[1][0]=fmaf(ev2.y,mv2.x,as[1][0]); as[1][1]=fmaf(ev2.y,mv2.y,as[1][1]);
      an[0][0]=fmaf(cv2.x,mv2.x,an[0][0]); an[0][1]=fmaf(cv2.x,mv2.y,an[0][1]);
      an[1][0]=fmaf(cv2.y,mv2.x,an[1][0]); an[1][1]=fmaf(cv2.y,mv2.y,an[1][1]);
    }
    __syncthreads();
  }
  float blg = blg_p[0];
  #pragma unroll
  for (int qq = 0; qq < 2; ++qq)
    #pragma unroll
    for (int ii = 0; ii < 2; ++ii){
      int q = q0 + tq*2 + qq, i = i0 + ti*2 + ii;
      size_t idx = (size_t)q*KN + i;
      float s = as[qq][ii], n = an[qq][ii];
      float lg = sigf(n/s + gl2[i] + blg);
      float gg = g[idx];
      wv[idx] = gg*lg/s; v2[idx] = gg*(1.f - lg);
    }
}

// kcC: u = wv @ M over i; epilogue coef = u*ev + v2. grid (16,8), 32q x 32j tile.
__global__ __launch_bounds__(256) void kcC(const int* __restrict__ kadj,
                                           const float* __restrict__ wvp, const float* __restrict__ ev,
                                           const float* __restrict__ v2, float* __restrict__ coef){
  __shared__ float sW[64][34];  // [i][q]
  __shared__ float sM[64][34];  // [i][j]
  int t = threadIdx.x;
  int q0 = blockIdx.y*32, j0 = blockIdx.x*32;
  int tq = t & 15, tj = t >> 4;
  float u[2][2] = {{0.f,0.f},{0.f,0.f}};
  for (int i0 = 0; i0 < KN; i0 += 64){
    #pragma unroll
    for (int r = 0; r < 2; ++r){
      int f = t + 256*r;
      { int row = f >> 4; int c4 = (f & 15)*4;
        float4 vw = *(const float4*)(wvp + (size_t)(q0+row)*KN + i0 + c4);
        sW[c4+0][row]=vw.x; sW[c4+1][row]=vw.y; sW[c4+2][row]=vw.z; sW[c4+3][row]=vw.w; }
      { int i = f >> 3; int j4 = (f & 7)*4;
        int4 vm = *(const int4*)(kadj + (size_t)(i0+i)*KN + j0 + j4);
        sM[i][j4+0]=vm.x?1.f:0.f; sM[i][j4+1]=vm.y?1.f:0.f;
        sM[i][j4+2]=vm.z?1.f:0.f; sM[i][j4+3]=vm.w?1.f:0.f; }
    }
    __syncthreads();
    #pragma unroll 8
    for (int i = 0; i < 64; ++i){
      float2 w2 = *(const float2*)&sW[i][tq*2];
      float2 m2 = *(const float2*)&sM[i][tj*2];
      u[0][0]=fmaf(w2.x,m2.x,u[0][0]); u[0][1]=fmaf(w2.x,m2.y,u[0][1]);
      u[1][0]=fmaf(w2.y,m2.x,u[1][0]); u[1][1]=fmaf(w2.y,m2.y,u[1][1]);
    }
    __syncthreads();
  }
  #pragma unroll
  for (int qq = 0; qq < 2; ++qq)
    #pragma unroll
    for (int jj = 0; jj < 2; ++jj){
      int q = q0 + tq*2 + qq, j = j0 + tj*2 + jj;
      size_t idx = (size_t)q*KN + j;
      coef[idx] = u[qq][jj]*ev[idx] + v2[idx];
    }
}

// kc4g: k_matmul = coef @ k_enc2. grid (8,8), 32q x 32d tile.
__global__ __launch_bounds__(256) void kc4g(const float* __restrict__ coef,
                                            const float* __restrict__ ke2,
                                            float* __restrict__ km){
  __shared__ float sC[64][34];  // [k][q]
  __shared__ float sB[64][34];  // [k][d]
  int t = threadIdx.x;
  int q0 = blockIdx.y*32, d0 = blockIdx.x*32;
  int tq = t & 15, td = t >> 4;
  float acc[2][2] = {{0.f,0.f},{0.f,0.f}};
  for (int k0 = 0; k0 < KN; k0 += 64){
    #pragma unroll
    for (int r = 0; r < 2; ++r){
      int f = t + 256*r;
      { int row = f >> 4; int c4 = (f & 15)*4;
        float4 vc = *(const float4*)(coef + (size_t)(q0+row)*KN + k0 + c4);
        sC[c4+0][row]=vc.x; sC[c4+1][row]=vc.y; sC[c4+2][row]=vc.z; sC[c4+3][row]=vc.w; }
      { int k = f >> 3; int d4 = (f & 7)*4;
        float4 vb = *(const float4*)(ke2 + (size_t)(k0+k)*DN + d0 + d4);
        sB[k][d4+0]=vb.x; sB[k][d4+1]=vb.y; sB[k][d4+2]=vb.z; sB[k][d4+3]=vb.w; }
    }
    __syncthreads();
    #pragma unroll 8
    for (int k = 0; k < 64; ++k){
      float2 c2 = *(const float2*)&sC[k][tq*2];
      float2 b2 = *(const float2*)&sB[k][td*2];
      acc[0][0]=fmaf(c2.x,b2.x,acc[0][0]); acc[0][1]=fmaf(c2.x,b2.y,acc[0][1]);
      acc[1][0]=fmaf(c2.y,b2.x,acc[1][0]); acc[1][1]=fmaf(c2.y,b2.y,acc[1][1]);
    }
    __syncthreads();
  }
  #pragma unroll
  for (int qq = 0; qq < 2; ++qq)
    #pragma unroll
    for (int dd = 0; dd < 2; ++dd){
      int q = q0 + tq*2 + qq, d = d0 + td*2 + dd;
      km[(size_t)q*DN + d] = acc[qq][dd];
    }
}

// KD (big pass 2): k_r_matmul partials. grid (8 k-splits, 256 q).
__global__ void kd_relv(const float* __restrict__ rel_v, const float* __restrict__ g,
                        float* __restrict__ part){
  int s = blockIdx.x, q = blockIdx.y;
  int t = threadIdx.x, w = t >> 6, lane = t & 63;
  __shared__ float4 lacc[4][64];
  float4 acc = make_float4(0.f, 0.f, 0.f, 0.f);
  int kbase = s*64 + w*16;
  for (int tt = 0; tt < 16; ++tt){
    int k = kbase + tt;
    float a = g[q*KN + k];
    float4 x = ((const float4*)(rel_v + (size_t)(q*KN + k)*DN))[lane];
    acc.x = fmaf(a, x.x, acc.x); acc.y = fmaf(a, x.y, acc.y);
    acc.z = fmaf(a, x.z, acc.z); acc.w = fmaf(a, x.w, acc.w);
  }
  lacc[w][lane] = acc;
  __syncthreads();
  if (t < 64){
    float4 r = lacc[0][t], b = lacc[1][t], c = lacc[2][t], d4 = lacc[3][t];
    r.x += b.x + c.x + d4.x; r.y += b.y + c.y + d4.y;
    r.z += b.z + c.z + d4.z; r.w += b.w + c.w + d4.w;
    ((float4*)(part + (size_t)(s*QN + q)*DN))[t] = r;
  }
}

// KE (block per q): q_enc_new = k_matmul + Σ part; gate; h
__global__ void ke_out(const float* __restrict__ part, const float* __restrict__ k_matmul,
                       const float* __restrict__ q_enc, const float* __restrict__ W_gate,
                       const float* __restrict__ b_gate, float* __restrict__ out){
  int q = blockIdx.x, t = threadIdx.x;
  __shared__ float red[DN];
  float qen = k_matmul[q*DN + t];
  #pragma unroll
  for (int s = 0; s < 8; ++s) qen += part[(size_t)(s*QN + q)*DN + t];
  float qe = q_enc[q*DN + t];
  float dot = block_reduce_sum256(qen*W_gate[t] + qe*W_gate[DN + t], red);
  float gate = sigf(dot + b_gate[0]);
  out[q*DN + t] = gate*qen + (1.f - gate)*qe;
}

extern "C" void kernel_launch(void* const* d_in, const int* in_sizes, int n_in,
                              void* d_out, int out_size, void* d_ws, size_t ws_size,
                              hipStream_t stream){
  const float* q_enc     = (const float*)d_in[0];
  const float* k_enc     = (const float*)d_in[1];
  const float* rel_k     = (const float*)d_in[2];
  const float* rel_v     = (const float*)d_in[3];
  const int*   k_adj     = (const int*)  d_in[4];
  const float* W_glob    = (const float*)d_in[5];
  const float* b_glob    = (const float*)d_in[6];
  const float* W_gv0     = (const float*)d_in[7];
  const float* b_gv0     = (const float*)d_in[8];
  const float* W_gv1     = (const float*)d_in[9];
  const float* b_gv1     = (const float*)d_in[10];
  const float* W_gq      = (const float*)d_in[11];
  const float* b_gq      = (const float*)d_in[12];
  const float* W_lq      = (const float*)d_in[13];
  const float* b_lq      = (const float*)d_in[14];
  const float* W_locgate = (const float*)d_in[15];
  const float* b_locgate = (const float*)d_in[16];
  const float* W_gate    = (const float*)d_in[17];
  const float* b_gate    = (const float*)d_in[18];
  float* out = (float*)d_out;

  float* ws = (float*)d_ws;
  float* tmp_glob = ws;                    // 256
  float* g1       = tmp_glob + 256;        // 256
  float* k_enc2   = g1 + 256;              // 131072
  float* cvec     = k_enc2 + 131072;       // 512
  float* gl2      = cvec + 512;            // 512
  float* q_glob   = gl2 + 512;             // 65536
  float* q_loc    = q_glob + 65536;        // 65536
  float* qk_r     = q_loc + 65536;         // 131072  (reused as exs after kcL)
  float* qnk_r    = qk_r + 131072;         // 131072
  float* gat      = qnk_r + 131072;        // 131072
  float* ev       = gat + 131072;          // 131072
  float* ecv      = ev + 131072;           // 131072
  float* wv       = ecv + 131072;          // 131072
  float* v2       = wv + 131072;           // 131072
  float* coef     = v2 + 131072;           // 131072
  float* k_matmul = coef + 131072;         // 65536
  float* part     = k_matmul + 65536;      // 8*65536 = 524288

  k1_prep<<<1, 256, 0, stream>>>(q_enc, W_glob, b_glob, W_gv0, b_gv0, tmp_glob, g1);
  k2_kenc2<<<512, 256, 0, stream>>>(k_enc, W_gv1, b_gv1, tmp_glob, g1, W_locgate,
                                    k_enc2, cvec, gl2);
  k3_qproj<<<256, 256, 0, stream>>>(q_enc, W_gq, b_gq, W_lq, b_lq, q_glob, q_loc);
  kb_relk<<<32768, 256, 0, stream>>>(rel_k, q_glob, q_loc, qk_r, qnk_r);
  kcL<<<dim3(16, 8), 256, 0, stream>>>(q_glob, q_loc, k_enc2, cvec, qk_r, qnk_r, ev, ecv);
  kcS<<<256, 256, 0, stream>>>(qk_r, gat);
  kcA<<<dim3(16, 8), 256, 0, stream>>>(k_adj, ev, ecv, gat, gl2, b_locgate, wv, v2);
  kcC<<<dim3(16, 8), 256, 0, stream>>>(k_adj, wv, ev, v2, coef);
  kc4g<<<dim3(8, 8), 256, 0, stream>>>(coef, k_enc2, k_matmul);
  kd_relv<<<dim3(8, 256), 256, 0, stream>>>(rel_v, gat, part);
  ke_out<<<256, 256, 0, stream>>>(part, k_matmul, q_enc, W_gate, b_gate, out);
}

// Round 3
// 129.516 us; speedup vs baseline: 2.6028x; 1.3944x over previous
//
#include <hip/hip_runtime.h>
#include <math.h>

#define QN 256
#define KN 512
#define DN 256
#define SCALE 0.0625f  // 1/sqrt(256)

__device__ __forceinline__ float sigf(float x){ return 1.0f/(1.0f+expf(-x)); }

__device__ __forceinline__ float block_reduce_sum256(float v, float* red){
  int t = threadIdx.x;
  red[t] = v; __syncthreads();
  #pragma unroll
  for (int s = 128; s > 0; s >>= 1){
    if (t < s) red[t] += red[t+s];
    __syncthreads();
  }
  float r = red[0];
  __syncthreads();
  return r;
}

// kA2 (32 blocks x 256): block b: qmean for cols [8b,8b+8) + GEMV partials for both weights
__global__ void kA2(const float* __restrict__ q_enc,
                    const float* __restrict__ W_glob, const float* __restrict__ W_gv0,
                    float* __restrict__ party0, float* __restrict__ party1){
  __shared__ float sm[256][9];
  __shared__ float qm[8];
  int b = blockIdx.x, t = threadIdx.x;
  int j0 = b*8;
  float4 lo = *(const float4*)(q_enc + (size_t)t*DN + j0);
  float4 hi = *(const float4*)(q_enc + (size_t)t*DN + j0 + 4);
  sm[t][0]=lo.x; sm[t][1]=lo.y; sm[t][2]=lo.z; sm[t][3]=lo.w;
  sm[t][4]=hi.x; sm[t][5]=hi.y; sm[t][6]=hi.z; sm[t][7]=hi.w;
  __syncthreads();
  #pragma unroll
  for (int s = 128; s > 0; s >>= 1){
    if (t < s){
      #pragma unroll
      for (int j = 0; j < 8; ++j) sm[t][j] += sm[t+s][j];
    }
    __syncthreads();
  }
  if (t < 8) qm[t] = sm[0][t] * (1.0f/QN);
  __syncthreads();
  float a0 = 0.f, a1 = 0.f;
  #pragma unroll
  for (int j = 0; j < 8; ++j){
    float s = qm[j];
    a0 = fmaf(s, W_glob[(size_t)(j0+j)*DN + t], a0);
    a1 = fmaf(s, W_gv0[(size_t)(j0+j)*DN + t], a1);
  }
  party0[b*256 + t] = a0; party1[b*256 + t] = a1;
}

// kA3 (1 block): reduce 32 partials + bias -> tmp_glob, g1
__global__ void kA3(const float* __restrict__ party0, const float* __restrict__ party1,
                    const float* __restrict__ b_glob, const float* __restrict__ b_gv0,
                    float* __restrict__ tmp_glob, float* __restrict__ g1){
  int t = threadIdx.x;
  float a0 = b_glob[t], a1 = b_gv0[t];
  #pragma unroll
  for (int b = 0; b < 32; ++b){ a0 += party0[b*256 + t]; a1 += party1[b*256 + t]; }
  tmp_glob[t] = a0; g1[t] = a1;
}

// k23 (768 blocks): bid<512 -> k2 body (k=bid); else k3 body (q=bid-512)
__global__ void k23(const float* __restrict__ k_enc,
                    const float* __restrict__ W_gv1, const float* __restrict__ b_gv1,
                    const float* __restrict__ tmp_glob, const float* __restrict__ g1,
                    const float* __restrict__ W_locgate,
                    float* __restrict__ k_enc2, float* __restrict__ cvec,
                    float* __restrict__ gl2,
                    const float* __restrict__ q_enc,
                    const float* __restrict__ W_gq, const float* __restrict__ b_gq,
                    const float* __restrict__ W_lq, const float* __restrict__ b_lq,
                    float* __restrict__ q_glob, float* __restrict__ q_loc){
  __shared__ float sh1[256];
  __shared__ float sh2[256];
  int bid = blockIdx.x, t = threadIdx.x;
  if (bid < 512){
    int k = bid;
    float kv = k_enc[(size_t)k*DN + t];
    sh1[t] = kv;
    float dot = block_reduce_sum256(kv * tmp_glob[t], sh2);
    float ks = sigf(dot * SCALE);
    float acc = b_gv1[t];
    for (int j = 0; j < DN; ++j) acc = fmaf(sh1[j], W_gv1[(size_t)j*DN + t], acc);
    float v = (1.f - ks)*acc + ks*g1[t];
    k_enc2[(size_t)k*DN + t] = v;
    float c  = block_reduce_sum256(v * W_locgate[t],      sh2);
    float g2 = block_reduce_sum256(v * W_locgate[DN + t], sh2);
    if (t == 0){ cvec[k] = c; gl2[k] = g2; }
  } else {
    int q = bid - 512;
    sh1[t] = q_enc[(size_t)q*DN + t];
    __syncthreads();
    float a = b_gq[t], b = b_lq[t];
    for (int j = 0; j < DN; ++j){
      float s = sh1[j];
      a = fmaf(s, W_gq[(size_t)j*DN + t], a);
      b = fmaf(s, W_lq[(size_t)j*DN + t], b);
    }
    q_glob[(size_t)q*DN + t] = a; q_loc[(size_t)q*DN + t] = b;
  }
}

// KB: one wave per (q,k): qk_r = q_glob·rel_k[q,k]; qnk_r with q_loc
__global__ void kb_relk(const float* __restrict__ rel_k,
                        const float* __restrict__ q_glob, const float* __restrict__ q_loc,
                        float* __restrict__ qk_r, float* __restrict__ qnk_r){
  int w = blockIdx.x*4 + (threadIdx.x >> 6);
  int lane = threadIdx.x & 63;
  int q = w >> 9, k = w & 511;
  const float4* rk = (const float4*)(rel_k + (size_t)(q*KN + k)*DN);
  float4 x = rk[lane];
  float4 a = ((const float4*)(q_glob + q*DN))[lane];
  float4 b = ((const float4*)(q_loc  + q*DN))[lane];
  float p1 = x.x*a.x + x.y*a.y + x.z*a.z + x.w*a.w;
  float p2 = x.x*b.x + x.y*b.y + x.z*b.z + x.w*b.w;
  #pragma unroll
  for (int off = 32; off; off >>= 1){ p1 += __shfl_down(p1, off); p2 += __shfl_down(p2, off); }
  if (lane == 0){ qk_r[q*KN + k] = p1; qnk_r[q*KN + k] = p2; }
}

// kcL (grid (16,16), 128 thr): 16q x 32k dual GEMM + epilogue (exs->qkr, ev, ec)
__global__ __launch_bounds__(128) void kcL(const float* __restrict__ qg, const float* __restrict__ ql,
                                           const float* __restrict__ ke2, const float* __restrict__ cvec,
                                           float* __restrict__ qkr, const float* __restrict__ qnkr,
                                           float* __restrict__ ev, float* __restrict__ ec){
  __shared__ float sA[64][18], sL[64][18], sB[64][34];
  int t = threadIdx.x;
  int q0 = blockIdx.y*16, k0 = blockIdx.x*32;
  int tq = t & 7, tk = t >> 3;
  float a1[2][2] = {{0.f,0.f},{0.f,0.f}}, a2[2][2] = {{0.f,0.f},{0.f,0.f}};
  for (int d0 = 0; d0 < DN; d0 += 64){
    #pragma unroll
    for (int r = 0; r < 2; ++r){
      int f = t + 128*r; int row = f >> 4; int c4 = (f & 15)*4;
      float4 va = *(const float4*)(qg + (size_t)(q0+row)*DN + d0 + c4);
      float4 vl = *(const float4*)(ql + (size_t)(q0+row)*DN + d0 + c4);
      sA[c4+0][row]=va.x; sA[c4+1][row]=va.y; sA[c4+2][row]=va.z; sA[c4+3][row]=va.w;
      sL[c4+0][row]=vl.x; sL[c4+1][row]=vl.y; sL[c4+2][row]=vl.z; sL[c4+3][row]=vl.w;
    }
    #pragma unroll
    for (int r = 0; r < 4; ++r){
      int f = t + 128*r; int row = f >> 4; int c4 = (f & 15)*4;
      float4 vb = *(const float4*)(ke2 + (size_t)(k0+row)*DN + d0 + c4);
      sB[c4+0][row]=vb.x; sB[c4+1][row]=vb.y; sB[c4+2][row]=vb.z; sB[c4+3][row]=vb.w;
    }
    __syncthreads();
    #pragma unroll 8
    for (int d = 0; d < 64; ++d){
      float2 av = *(const float2*)&sA[d][tq*2];
      float2 lv = *(const float2*)&sL[d][tq*2];
      float2 bv = *(const float2*)&sB[d][tk*2];
      a1[0][0] = fmaf(av.x, bv.x, a1[0][0]); a1[0][1] = fmaf(av.x, bv.y, a1[0][1]);
      a1[1][0] = fmaf(av.y, bv.x, a1[1][0]); a1[1][1] = fmaf(av.y, bv.y, a1[1][1]);
      a2[0][0] = fmaf(lv.x, bv.x, a2[0][0]); a2[0][1] = fmaf(lv.x, bv.y, a2[0][1]);
      a2[1][0] = fmaf(lv.y, bv.x, a2[1][0]); a2[1][1] = fmaf(lv.y, bv.y, a2[1][1]);
    }
    __syncthreads();
  }
  #pragma unroll
  for (int qq = 0; qq < 2; ++qq)
    #pragma unroll
    for (int kk = 0; kk < 2; ++kk){
      int q = q0 + tq*2 + qq, k = k0 + tk*2 + kk;
      size_t idx = (size_t)q*KN + k;
      float p1 = a1[qq][kk] + qkr[idx];
      qkr[idx] = expf(tanhf(p1*SCALE));          // exs (unnormalized glob numerator)
      float p2 = a2[qq][kk] + qnkr[idx];
      float evv = expf(tanhf(p2*SCALE));
      ev[idx] = evv; ec[idx] = evv*cvec[k];
    }
}

// kcA2 (grid (16,16), 128 thr): 16q x 32i dual masked GEMM {e,ec}@M^T + epilogue wv', v2'
__global__ __launch_bounds__(128) void kcA2(const int* __restrict__ kadj,
                                            const float* __restrict__ e, const float* __restrict__ ecp,
                                            const float* __restrict__ exs, const float* __restrict__ gl2,
                                            const float* __restrict__ blg_p,
                                            float* __restrict__ wv, float* __restrict__ v2){
  __shared__ float sE[64][18], sC[64][18], sM[64][34];
  int t = threadIdx.x;
  int q0 = blockIdx.y*16, i0 = blockIdx.x*32;
  int tq = t & 7, ti = t >> 3;
  float as[2][2] = {{0.f,0.f},{0.f,0.f}}, an[2][2] = {{0.f,0.f},{0.f,0.f}};
  for (int j0 = 0; j0 < KN; j0 += 64){
    #pragma unroll
    for (int r = 0; r < 2; ++r){
      int f = t + 128*r; int row = f >> 4; int c4 = (f & 15)*4;
      float4 vE = *(const float4*)(e   + (size_t)(q0+row)*KN + j0 + c4);
      float4 vC = *(const float4*)(ecp + (size_t)(q0+row)*KN + j0 + c4);
      sE[c4+0][row]=vE.x; sE[c4+1][row]=vE.y; sE[c4+2][row]=vE.z; sE[c4+3][row]=vE.w;
      sC[c4+0][row]=vC.x; sC[c4+1][row]=vC.y; sC[c4+2][row]=vC.z; sC[c4+3][row]=vC.w;
    }
    #pragma unroll
    for (int r = 0; r < 4; ++r){
      int f = t + 128*r; int row = f >> 4; int c4 = (f & 15)*4;
      int4 vM = *(const int4*)(kadj + (size_t)(i0+row)*KN + j0 + c4);
      sM[c4+0][row]=vM.x?1.f:0.f; sM[c4+1][row]=vM.y?1.f:0.f;
      sM[c4+2][row]=vM.z?1.f:0.f; sM[c4+3][row]=vM.w?1.f:0.f;
    }
    __syncthreads();
    #pragma unroll 8
    for (int j = 0; j < 64; ++j){
      float2 ev2 = *(const float2*)&sE[j][tq*2];
      float2 cv2 = *(const float2*)&sC[j][tq*2];
      float2 mv2 = *(const float2*)&sM[j][ti*2];
      as[0][0]=fmaf(ev2.x,mv2.x,as[0][0]); as[0][1]=fmaf(ev2.x,mv2.y,as[0][1]);
      as[1][0]=fmaf(ev2.y,mv2.x,as[1][0]); as[1][1]=fmaf(ev2.y,mv2.y,as[1][1]);
      an[0][0]=fmaf(cv2.x,mv2.x,an[0][0]); an[0][1]=fmaf(cv2.x,mv2.y,an[0][1]);
      an[1][0]=fmaf(cv2.y,mv2.x,an[1][0]); an[1][1]=fmaf(cv2.y,mv2.y,an[1][1]);
    }
    __syncthreads();
  }
  float blg = blg_p[0];
  #pragma unroll
  for (int qq = 0; qq < 2; ++qq)
    #pragma unroll
    for (int ii = 0; ii < 2; ++ii){
      int q = q0 + tq*2 + qq, i = i0 + ti*2 + ii;
      size_t idx = (size_t)q*KN + i;
      float s = as[qq][ii], n = an[qq][ii];
      float lg = sigf(n/s + gl2[i] + blg);
      float ex = exs[idx];
      wv[idx] = ex*lg/s; v2[idx] = ex*(1.f - lg);   // unnormalized (×invs applied in kDE)
    }
}

// kcC2 (grid (16,16), 128 thr): u' = wv' @ M over i; coef' = u'*ev + v2'
__global__ __launch_bounds__(128) void kcC2(const int* __restrict__ kadj,
                                            const float* __restrict__ wvp, const float* __restrict__ ev,
                                            const float* __restrict__ v2, float* __restrict__ coef){
  __shared__ float sW[64][18];  // [i][q]
  __shared__ float sM[64][34];  // [i][j]
  int t = threadIdx.x;
  int q0 = blockIdx.y*16, j0 = blockIdx.x*32;
  int tq = t & 7, tj = t >> 3;
  float u[2][2] = {{0.f,0.f},{0.f,0.f}};
  for (int i0 = 0; i0 < KN; i0 += 64){
    #pragma unroll
    for (int r = 0; r < 2; ++r){
      int f = t + 128*r; int row = f >> 4; int c4 = (f & 15)*4;
      float4 vw = *(const float4*)(wvp + (size_t)(q0+row)*KN + i0 + c4);
      sW[c4+0][row]=vw.x; sW[c4+1][row]=vw.y; sW[c4+2][row]=vw.z; sW[c4+3][row]=vw.w;
    }
    #pragma unroll
    for (int r = 0; r < 4; ++r){
      int f = t + 128*r; int i = f >> 3; int j4 = (f & 7)*4;
      int4 vm = *(const int4*)(kadj + (size_t)(i0+i)*KN + j0 + j4);
      sM[i][j4+0]=vm.x?1.f:0.f; sM[i][j4+1]=vm.y?1.f:0.f;
      sM[i][j4+2]=vm.z?1.f:0.f; sM[i][j4+3]=vm.w?1.f:0.f;
    }
    __syncthreads();
    #pragma unroll 8
    for (int i = 0; i < 64; ++i){
      float2 w2 = *(const float2*)&sW[i][tq*2];
      float2 m2 = *(const float2*)&sM[i][tj*2];
      u[0][0]=fmaf(w2.x,m2.x,u[0][0]); u[0][1]=fmaf(w2.x,m2.y,u[0][1]);
      u[1][0]=fmaf(w2.y,m2.x,u[1][0]); u[1][1]=fmaf(w2.y,m2.y,u[1][1]);
    }
    __syncthreads();
  }
  #pragma unroll
  for (int qq = 0; qq < 2; ++qq)
    #pragma unroll
    for (int jj = 0; jj < 2; ++jj){
      int q = q0 + tq*2 + qq, j = j0 + tj*2 + jj;
      size_t idx = (size_t)q*KN + j;
      coef[idx] = u[qq][jj]*ev[idx] + v2[idx];
    }
}

// kDE (grid 256, 512 thr): invs from exs row; acc = Σ_k exs*rel_v + coef'*k_enc2; ×invs; gate -> out
__global__ __launch_bounds__(512) void kDE(const float* __restrict__ relv,
                                           const float* __restrict__ ke2,
                                           const float* __restrict__ exs,
                                           const float* __restrict__ coef,
                                           const float* __restrict__ q_enc,
                                           const float* __restrict__ W_gate,
                                           const float* __restrict__ b_gate,
                                           float* __restrict__ out){
  __shared__ float red[512];
  __shared__ float4 pacc[8][64];
  int q = blockIdx.x, t = threadIdx.x, w = t >> 6, lane = t & 63;
  red[t] = exs[(size_t)q*KN + t];
  __syncthreads();
  #pragma unroll
  for (int s = 256; s > 0; s >>= 1){
    if (t < s) red[t] += red[t+s];
    __syncthreads();
  }
  float invs = 1.0f / red[0];
  float4 acc = make_float4(0.f,0.f,0.f,0.f);
  int kbase = w*64;
  #pragma unroll 4
  for (int kk = 0; kk < 64; ++kk){
    int k = kbase + kk;
    float gk = exs[(size_t)q*KN + k];
    float ck = coef[(size_t)q*KN + k];
    float4 xv = ((const float4*)(relv + (size_t)(q*KN + k)*DN))[lane];
    float4 kv = ((const float4*)(ke2 + (size_t)k*DN))[lane];
    acc.x = fmaf(gk, xv.x, fmaf(ck, kv.x, acc.x));
    acc.y = fmaf(gk, xv.y, fmaf(ck, kv.y, acc.y));
    acc.z = fmaf(gk, xv.z, fmaf(ck, kv.z, acc.z));
    acc.w = fmaf(gk, xv.w, fmaf(ck, kv.w, acc.w));
  }
  pacc[w][lane] = acc;
  __syncthreads();
  if (t < 64){
    float4 r = pacc[0][t];
    #pragma unroll
    for (int w2 = 1; w2 < 8; ++w2){
      float4 p = pacc[w2][t];
      r.x += p.x; r.y += p.y; r.z += p.z; r.w += p.w;
    }
    r.x *= invs; r.y *= invs; r.z *= invs; r.w *= invs;   // q_enc_new chunk
    float4 qe = ((const float4*)(q_enc + (size_t)q*DN))[t];
    float4 w1 = ((const float4*)(W_gate))[t];
    float4 w2v = ((const float4*)(W_gate + DN))[t];
    float pd = r.x*w1.x + r.y*w1.y + r.z*w1.z + r.w*w1.w
             + qe.x*w2v.x + qe.y*w2v.y + qe.z*w2v.z + qe.w*w2v.w;
    #pragma unroll
    for (int off = 32; off; off >>= 1) pd += __shfl_down(pd, off);
    float gate = sigf(__shfl(pd, 0) + b_gate[0]);
    float4 h;
    h.x = gate*r.x + (1.f-gate)*qe.x;
    h.y = gate*r.y + (1.f-gate)*qe.y;
    h.z = gate*r.z + (1.f-gate)*qe.z;
    h.w = gate*r.w + (1.f-gate)*qe.w;
    ((float4*)(out + (size_t)q*DN))[t] = h;
  }
}

extern "C" void kernel_launch(void* const* d_in, const int* in_sizes, int n_in,
                              void* d_out, int out_size, void* d_ws, size_t ws_size,
                              hipStream_t stream){
  const float* q_enc     = (const float*)d_in[0];
  const float* k_enc     = (const float*)d_in[1];
  const float* rel_k     = (const float*)d_in[2];
  const float* rel_v     = (const float*)d_in[3];
  const int*   k_adj     = (const int*)  d_in[4];
  const float* W_glob    = (const float*)d_in[5];
  const float* b_glob    = (const float*)d_in[6];
  const float* W_gv0     = (const float*)d_in[7];
  const float* b_gv0     = (const float*)d_in[8];
  const float* W_gv1     = (const float*)d_in[9];
  const float* b_gv1     = (const float*)d_in[10];
  const float* W_gq      = (const float*)d_in[11];
  const float* b_gq      = (const float*)d_in[12];
  const float* W_lq      = (const float*)d_in[13];
  const float* b_lq      = (const float*)d_in[14];
  const float* W_locgate = (const float*)d_in[15];
  const float* b_locgate = (const float*)d_in[16];
  const float* W_gate    = (const float*)d_in[17];
  const float* b_gate    = (const float*)d_in[18];
  float* out = (float*)d_out;

  float* ws = (float*)d_ws;
  float* party0   = ws;                    // 8192
  float* party1   = party0 + 8192;         // 8192
  float* tmp_glob = party1 + 8192;         // 256
  float* g1       = tmp_glob + 256;        // 256
  float* k_enc2   = g1 + 256;              // 131072
  float* cvec     = k_enc2 + 131072;       // 512
  float* gl2      = cvec + 512;            // 512
  float* q_glob   = gl2 + 512;             // 65536
  float* q_loc    = q_glob + 65536;        // 65536
  float* qk_r     = q_loc + 65536;         // 131072 (becomes exs after kcL)
  float* qnk_r    = qk_r + 131072;         // 131072
  float* evb      = qnk_r + 131072;        // 131072
  float* ecb      = evb + 131072;          // 131072
  float* wv       = ecb + 131072;          // 131072
  float* v2       = wv + 131072;           // 131072
  float* coef     = v2 + 131072;           // 131072

  kA2<<<32, 256, 0, stream>>>(q_enc, W_glob, W_gv0, party0, party1);
  kA3<<<1, 256, 0, stream>>>(party0, party1, b_glob, b_gv0, tmp_glob, g1);
  k23<<<768, 256, 0, stream>>>(k_enc, W_gv1, b_gv1, tmp_glob, g1, W_locgate,
                               k_enc2, cvec, gl2,
                               q_enc, W_gq, b_gq, W_lq, b_lq, q_glob, q_loc);
  kb_relk<<<32768, 256, 0, stream>>>(rel_k, q_glob, q_loc, qk_r, qnk_r);
  kcL<<<dim3(16, 16), 128, 0, stream>>>(q_glob, q_loc, k_enc2, cvec, qk_r, qnk_r, evb, ecb);
  kcA2<<<dim3(16, 16), 128, 0, stream>>>(k_adj, evb, ecb, qk_r, gl2, b_locgate, wv, v2);
  kcC2<<<dim3(16, 16), 128, 0, stream>>>(k_adj, wv, evb, v2, coef);
  kDE<<<256, 512, 0, stream>>>(rel_v, k_enc2, qk_r, coef, q_enc, W_gate, b_gate, out);
}

// Round 4
// 108.488 us; speedup vs baseline: 3.1073x; 1.1938x over previous
//
#include <hip/hip_runtime.h>
#include <math.h>

#define QN 256
#define KN 512
#define DN 256
#define SCALE 0.0625f  // 1/sqrt(256)

typedef __attribute__((ext_vector_type(8))) short short8v;
typedef __attribute__((ext_vector_type(4))) float f32x4;

__device__ __forceinline__ float sigf(float x){ return 1.0f/(1.0f+expf(-x)); }

__device__ __forceinline__ unsigned short f2bf(float x){
  unsigned u = __float_as_uint(x);
  unsigned r = (u + 0x7FFFu + ((u >> 16) & 1u)) >> 16;
  return (unsigned short)r;
}

// load 8 bf16 from LDS: elems 0-3 at p[0..3], elems 4-7 at p[16..19] (two K-halves)
__device__ __forceinline__ short8v ld8(const unsigned short* p){
  ushort4 a = *(const ushort4*)p;
  ushort4 b = *(const ushort4*)(p + 16);
  short8v r;
  r[0]=(short)a.x; r[1]=(short)a.y; r[2]=(short)a.z; r[3]=(short)a.w;
  r[4]=(short)b.x; r[5]=(short)b.y; r[6]=(short)b.z; r[7]=(short)b.w;
  return r;
}

__device__ __forceinline__ float block_reduce_sum256(float v, float* red){
  int t = threadIdx.x;
  red[t] = v; __syncthreads();
  #pragma unroll
  for (int s = 128; s > 0; s >>= 1){
    if (t < s) red[t] += red[t+s];
    __syncthreads();
  }
  float r = red[0];
  __syncthreads();
  return r;
}

// kA2 (32 blocks x 256): block b: qmean for cols [8b,8b+8) + GEMV partials for both weights
__global__ void kA2(const float* __restrict__ q_enc,
                    const float* __restrict__ W_glob, const float* __restrict__ W_gv0,
                    float* __restrict__ party0, float* __restrict__ party1){
  __shared__ float sm[256][9];
  __shared__ float qm[8];
  int b = blockIdx.x, t = threadIdx.x;
  int j0 = b*8;
  float4 lo = *(const float4*)(q_enc + (size_t)t*DN + j0);
  float4 hi = *(const float4*)(q_enc + (size_t)t*DN + j0 + 4);
  sm[t][0]=lo.x; sm[t][1]=lo.y; sm[t][2]=lo.z; sm[t][3]=lo.w;
  sm[t][4]=hi.x; sm[t][5]=hi.y; sm[t][6]=hi.z; sm[t][7]=hi.w;
  __syncthreads();
  #pragma unroll
  for (int s = 128; s > 0; s >>= 1){
    if (t < s){
      #pragma unroll
      for (int j = 0; j < 8; ++j) sm[t][j] += sm[t+s][j];
    }
    __syncthreads();
  }
  if (t < 8) qm[t] = sm[0][t] * (1.0f/QN);
  __syncthreads();
  float a0 = 0.f, a1 = 0.f;
  #pragma unroll
  for (int j = 0; j < 8; ++j){
    float s = qm[j];
    a0 = fmaf(s, W_glob[(size_t)(j0+j)*DN + t], a0);
    a1 = fmaf(s, W_gv0[(size_t)(j0+j)*DN + t], a1);
  }
  party0[b*256 + t] = a0; party1[b*256 + t] = a1;
}

// kA3 (1 block): reduce 32 partials + bias -> tmp_glob, g1
__global__ void kA3(const float* __restrict__ party0, const float* __restrict__ party1,
                    const float* __restrict__ b_glob, const float* __restrict__ b_gv0,
                    float* __restrict__ tmp_glob, float* __restrict__ g1){
  int t = threadIdx.x;
  float a0 = b_glob[t], a1 = b_gv0[t];
  #pragma unroll
  for (int b = 0; b < 32; ++b){ a0 += party0[b*256 + t]; a1 += party1[b*256 + t]; }
  tmp_glob[t] = a0; g1[t] = a1;
}

// k23 (768 blocks): bid<512 -> k2 body (k=bid); else k3 body (q=bid-512). Plus mask->bf16 convert.
__global__ void k23(const float* __restrict__ k_enc,
                    const float* __restrict__ W_gv1, const float* __restrict__ b_gv1,
                    const float* __restrict__ tmp_glob, const float* __restrict__ g1,
                    const float* __restrict__ W_locgate,
                    float* __restrict__ k_enc2, float* __restrict__ cvec,
                    float* __restrict__ gl2,
                    const float* __restrict__ q_enc,
                    const float* __restrict__ W_gq, const float* __restrict__ b_gq,
                    const float* __restrict__ W_lq, const float* __restrict__ b_lq,
                    float* __restrict__ q_glob, float* __restrict__ q_loc,
                    const int* __restrict__ kadj, unsigned short* __restrict__ mbf){
  __shared__ float sh1[256];
  __shared__ float sh2[256];
  int bid = blockIdx.x, t = threadIdx.x;
  // fused mask convert: 65536 int4 chunks over 196608 threads
  int gid = bid*256 + t;
  if (gid < 65536){
    int4 v = ((const int4*)kadj)[gid];
    ushort4 o;
    o.x = v.x ? 0x3F80 : 0; o.y = v.y ? 0x3F80 : 0;
    o.z = v.z ? 0x3F80 : 0; o.w = v.w ? 0x3F80 : 0;
    ((ushort4*)mbf)[gid] = o;
  }
  if (bid < 512){
    int k = bid;
    float kv = k_enc[(size_t)k*DN + t];
    sh1[t] = kv;
    float dot = block_reduce_sum256(kv * tmp_glob[t], sh2);
    float ks = sigf(dot * SCALE);
    float acc = b_gv1[t];
    for (int j = 0; j < DN; ++j) acc = fmaf(sh1[j], W_gv1[(size_t)j*DN + t], acc);
    float v = (1.f - ks)*acc + ks*g1[t];
    k_enc2[(size_t)k*DN + t] = v;
    float c  = block_reduce_sum256(v * W_locgate[t],      sh2);
    float g2 = block_reduce_sum256(v * W_locgate[DN + t], sh2);
    if (t == 0){ cvec[k] = c; gl2[k] = g2; }
  } else {
    int q = bid - 512;
    sh1[t] = q_enc[(size_t)q*DN + t];
    __syncthreads();
    float a = b_gq[t], b = b_lq[t];
    for (int j = 0; j < DN; ++j){
      float s = sh1[j];
      a = fmaf(s, W_gq[(size_t)j*DN + t], a);
      b = fmaf(s, W_lq[(size_t)j*DN + t], b);
    }
    q_glob[(size_t)q*DN + t] = a; q_loc[(size_t)q*DN + t] = b;
  }
}

// KB: one wave per (q,k): qk_r = q_glob·rel_k[q,k]; qnk_r with q_loc
__global__ void kb_relk(const float* __restrict__ rel_k,
                        const float* __restrict__ q_glob, const float* __restrict__ q_loc,
                        float* __restrict__ qk_r, float* __restrict__ qnk_r){
  int w = blockIdx.x*4 + (threadIdx.x >> 6);
  int lane = threadIdx.x & 63;
  int q = w >> 9, k = w & 511;
  const float4* rk = (const float4*)(rel_k + (size_t)(q*KN + k)*DN);
  float4 x = rk[lane];
  float4 a = ((const float4*)(q_glob + q*DN))[lane];
  float4 b = ((const float4*)(q_loc  + q*DN))[lane];
  float p1 = x.x*a.x + x.y*a.y + x.z*a.z + x.w*a.w;
  float p2 = x.x*b.x + x.y*b.y + x.z*b.z + x.w*b.w;
  #pragma unroll
  for (int off = 32; off; off >>= 1){ p1 += __shfl_down(p1, off); p2 += __shfl_down(p2, off); }
  if (lane == 0){ qk_r[q*KN + k] = p1; qnk_r[q*KN + k] = p2; }
}

// kcL (grid (16,16), 128 thr): 16q x 32k dual GEMM + epilogue (exs->qkr, ev, e_bf, ec_bf)
__global__ __launch_bounds__(128) void kcL(const float* __restrict__ qg, const float* __restrict__ ql,
                                           const float* __restrict__ ke2, const float* __restrict__ cvec,
                                           float* __restrict__ qkr, const float* __restrict__ qnkr,
                                           float* __restrict__ ev,
                                           unsigned short* __restrict__ ebf,
                                           unsigned short* __restrict__ ecbf){
  __shared__ float sA[64][18], sL[64][18], sB[64][34];
  int t = threadIdx.x;
  int q0 = blockIdx.y*16, k0 = blockIdx.x*32;
  int tq = t & 7, tk = t >> 3;
  float a1[2][2] = {{0.f,0.f},{0.f,0.f}}, a2[2][2] = {{0.f,0.f},{0.f,0.f}};
  for (int d0 = 0; d0 < DN; d0 += 64){
    #pragma unroll
    for (int r = 0; r < 2; ++r){
      int f = t + 128*r; int row = f >> 4; int c4 = (f & 15)*4;
      float4 va = *(const float4*)(qg + (size_t)(q0+row)*DN + d0 + c4);
      float4 vl = *(const float4*)(ql + (size_t)(q0+row)*DN + d0 + c4);
      sA[c4+0][row]=va.x; sA[c4+1][row]=va.y; sA[c4+2][row]=va.z; sA[c4+3][row]=va.w;
      sL[c4+0][row]=vl.x; sL[c4+1][row]=vl.y; sL[c4+2][row]=vl.z; sL[c4+3][row]=vl.w;
    }
    #pragma unroll
    for (int r = 0; r < 4; ++r){
      int f = t + 128*r; int row = f >> 4; int c4 = (f & 15)*4;
      float4 vb = *(const float4*)(ke2 + (size_t)(k0+row)*DN + d0 + c4);
      sB[c4+0][row]=vb.x; sB[c4+1][row]=vb.y; sB[c4+2][row]=vb.z; sB[c4+3][row]=vb.w;
    }
    __syncthreads();
    #pragma unroll 8
    for (int d = 0; d < 64; ++d){
      float2 av = *(const float2*)&sA[d][tq*2];
      float2 lv = *(const float2*)&sL[d][tq*2];
      float2 bv = *(const float2*)&sB[d][tk*2];
      a1[0][0] = fmaf(av.x, bv.x, a1[0][0]); a1[0][1] = fmaf(av.x, bv.y, a1[0][1]);
      a1[1][0] = fmaf(av.y, bv.x, a1[1][0]); a1[1][1] = fmaf(av.y, bv.y, a1[1][1]);
      a2[0][0] = fmaf(lv.x, bv.x, a2[0][0]); a2[0][1] = fmaf(lv.x, bv.y, a2[0][1]);
      a2[1][0] = fmaf(lv.y, bv.x, a2[1][0]); a2[1][1] = fmaf(lv.y, bv.y, a2[1][1]);
    }
    __syncthreads();
  }
  #pragma unroll
  for (int qq = 0; qq < 2; ++qq)
    #pragma unroll
    for (int kk = 0; kk < 2; ++kk){
      int q = q0 + tq*2 + qq, k = k0 + tk*2 + kk;
      size_t idx = (size_t)q*KN + k;
      float p1 = a1[qq][kk] + qkr[idx];
      qkr[idx] = expf(tanhf(p1*SCALE));          // exs (unnormalized glob numerator)
      float p2 = a2[qq][kk] + qnkr[idx];
      float evv = expf(tanhf(p2*SCALE));
      ev[idx] = evv;
      ebf[idx] = f2bf(evv);
      ecbf[idx] = f2bf(evv * cvec[k]);
    }
}

// kcA2m (grid (8,16), 256 thr): MFMA dual {e,ec}@M^T over j (K=512), tile 16q x 64i.
// Epilogue: lg = sig(an/as + gl2 + b); wv_bf = exs*lg/as; v2 = exs*(1-lg).
__global__ __launch_bounds__(256) void kcA2m(const unsigned short* __restrict__ ebf,
                                             const unsigned short* __restrict__ ecbf,
                                             const unsigned short* __restrict__ mbf,
                                             const float* __restrict__ exs,
                                             const float* __restrict__ gl2,
                                             const float* __restrict__ blg_p,
                                             unsigned short* __restrict__ wvbf,
                                             float* __restrict__ v2){
  __shared__ unsigned short Ae[16*520];
  __shared__ unsigned short Ac[16*520];
  __shared__ unsigned short Bm[64*520];
  int t = threadIdx.x;
  int i0 = blockIdx.x*64, q0 = blockIdx.y*16;
  #pragma unroll
  for (int it = 0; it < 4; ++it){
    int c = t + 256*it; int row = c >> 6, col = (c & 63)*8;
    *(uint4*)&Ae[row*520 + col] = *(const uint4*)&ebf[(size_t)(q0+row)*KN + col];
    *(uint4*)&Ac[row*520 + col] = *(const uint4*)&ecbf[(size_t)(q0+row)*KN + col];
  }
  #pragma unroll
  for (int it = 0; it < 16; ++it){
    int c = t + 256*it; int row = c >> 6, col = (c & 63)*8;
    *(uint4*)&Bm[row*520 + col] = *(const uint4*)&mbf[(size_t)(i0+row)*KN + col];
  }
  __syncthreads();
  int w = t >> 6, l = t & 63;
  int g16 = l >> 4, l16 = l & 15;
  f32x4 aS = {0.f,0.f,0.f,0.f}, aN = {0.f,0.f,0.f,0.f};
  const unsigned short* pe = &Ae[l16*520];
  const unsigned short* pc = &Ac[l16*520];
  const unsigned short* pb = &Bm[(16*w + l16)*520];
  #pragma unroll
  for (int kk = 0; kk < 16; ++kk){
    int k0 = kk*32 + 4*g16;
    short8v fa = ld8(pe + k0);
    short8v fc = ld8(pc + k0);
    short8v fb = ld8(pb + k0);
    aS = __builtin_amdgcn_mfma_f32_16x16x32_bf16(fa, fb, aS, 0, 0, 0);
    aN = __builtin_amdgcn_mfma_f32_16x16x32_bf16(fc, fb, aN, 0, 0, 0);
  }
  float blg = blg_p[0];
  int i = i0 + 16*w + l16;
  float gli = gl2[i];
  #pragma unroll
  for (int r = 0; r < 4; ++r){
    int q = q0 + 4*g16 + r;
    size_t idx = (size_t)q*KN + i;
    float s = aS[r], n = aN[r];
    float lgv = sigf(n/s + gli + blg);
    float ex = exs[idx];
    wvbf[idx] = f2bf(ex*lgv/s);
    v2[idx] = ex*(1.f - lgv);
  }
}

// kcC2m (grid (8,16), 256 thr): MFMA u = wv@M over i (K=512), tile 16q x 64j.
// Epilogue: coef = u*ev + v2.
__global__ __launch_bounds__(256) void kcC2m(const unsigned short* __restrict__ wvbf,
                                             const unsigned short* __restrict__ mbf,
                                             const float* __restrict__ ev,
                                             const float* __restrict__ v2,
                                             float* __restrict__ coef){
  __shared__ unsigned short Aw[16*520];
  __shared__ unsigned short Bm2[512*72];
  int t = threadIdx.x;
  int j0 = blockIdx.x*64, q0 = blockIdx.y*16;
  #pragma unroll
  for (int it = 0; it < 4; ++it){
    int c = t + 256*it; int row = c >> 6, col = (c & 63)*8;
    *(uint4*)&Aw[row*520 + col] = *(const uint4*)&wvbf[(size_t)(q0+row)*KN + col];
  }
  #pragma unroll
  for (int it = 0; it < 16; ++it){
    int c = t + 256*it; int row = c >> 3, col = (c & 7)*8;
    *(uint4*)&Bm2[row*72 + col] = *(const uint4*)&mbf[(size_t)row*KN + j0 + col];
  }
  __syncthreads();
  int w = t >> 6, l = t & 63;
  int g16 = l >> 4, l16 = l & 15;
  f32x4 aU = {0.f,0.f,0.f,0.f};
  const unsigned short* pa = &Aw[l16*520];
  int nn = 16*w + l16;
  #pragma unroll
  for (int kk = 0; kk < 16; ++kk){
    int k0 = kk*32 + 4*g16;
    short8v fa = ld8(pa + k0);
    short8v fb;
    #pragma unroll
    for (int e = 0; e < 4; ++e){
      fb[e]   = (short)Bm2[(k0+e)*72 + nn];
      fb[4+e] = (short)Bm2[(k0+16+e)*72 + nn];
    }
    aU = __builtin_amdgcn_mfma_f32_16x16x32_bf16(fa, fb, aU, 0, 0, 0);
  }
  int j = j0 + nn;
  #pragma unroll
  for (int r = 0; r < 4; ++r){
    int q = q0 + 4*g16 + r;
    size_t idx = (size_t)q*KN + j;
    coef[idx] = aU[r]*ev[idx] + v2[idx];
  }
}

// kDE (grid 256, 512 thr): invs from exs row; acc = Σ_k exs*rel_v + coef'*k_enc2; ×invs; gate -> out
__global__ __launch_bounds__(512) void kDE(const float* __restrict__ relv,
                                           const float* __restrict__ ke2,
                                           const float* __restrict__ exs,
                                           const float* __restrict__ coef,
                                           const float* __restrict__ q_enc,
                                           const float* __restrict__ W_gate,
                                           const float* __restrict__ b_gate,
                                           float* __restrict__ out){
  __shared__ float red[512];
  __shared__ float4 pacc[8][64];
  int q = blockIdx.x, t = threadIdx.x, w = t >> 6, lane = t & 63;
  red[t] = exs[(size_t)q*KN + t];
  __syncthreads();
  #pragma unroll
  for (int s = 256; s > 0; s >>= 1){
    if (t < s) red[t] += red[t+s];
    __syncthreads();
  }
  float invs = 1.0f / red[0];
  float4 acc = make_float4(0.f,0.f,0.f,0.f);
  int kbase = w*64;
  #pragma unroll 4
  for (int kk = 0; kk < 64; ++kk){
    int k = kbase + kk;
    float gk = exs[(size_t)q*KN + k];
    float ck = coef[(size_t)q*KN + k];
    float4 xv = ((const float4*)(relv + (size_t)(q*KN + k)*DN))[lane];
    float4 kv = ((const float4*)(ke2 + (size_t)k*DN))[lane];
    acc.x = fmaf(gk, xv.x, fmaf(ck, kv.x, acc.x));
    acc.y = fmaf(gk, xv.y, fmaf(ck, kv.y, acc.y));
    acc.z = fmaf(gk, xv.z, fmaf(ck, kv.z, acc.z));
    acc.w = fmaf(gk, xv.w, fmaf(ck, kv.w, acc.w));
  }
  pacc[w][lane] = acc;
  __syncthreads();
  if (t < 64){
    float4 r = pacc[0][t];
    #pragma unroll
    for (int w2 = 1; w2 < 8; ++w2){
      float4 p = pacc[w2][t];
      r.x += p.x; r.y += p.y; r.z += p.z; r.w += p.w;
    }
    r.x *= invs; r.y *= invs; r.z *= invs; r.w *= invs;
    float4 qe = ((const float4*)(q_enc + (size_t)q*DN))[t];
    float4 w1 = ((const float4*)(W_gate))[t];
    float4 w2v = ((const float4*)(W_gate + DN))[t];
    float pd = r.x*w1.x + r.y*w1.y + r.z*w1.z + r.w*w1.w
             + qe.x*w2v.x + qe.y*w2v.y + qe.z*w2v.z + qe.w*w2v.w;
    #pragma unroll
    for (int off = 32; off; off >>= 1) pd += __shfl_down(pd, off);
    float gate = sigf(__shfl(pd, 0) + b_gate[0]);
    float4 h;
    h.x = gate*r.x + (1.f-gate)*qe.x;
    h.y = gate*r.y + (1.f-gate)*qe.y;
    h.z = gate*r.z + (1.f-gate)*qe.z;
    h.w = gate*r.w + (1.f-gate)*qe.w;
    ((float4*)(out + (size_t)q*DN))[t] = h;
  }
}

extern "C" void kernel_launch(void* const* d_in, const int* in_sizes, int n_in,
                              void* d_out, int out_size, void* d_ws, size_t ws_size,
                              hipStream_t stream){
  const float* q_enc     = (const float*)d_in[0];
  const float* k_enc     = (const float*)d_in[1];
  const float* rel_k     = (const float*)d_in[2];
  const float* rel_v     = (const float*)d_in[3];
  const int*   k_adj     = (const int*)  d_in[4];
  const float* W_glob    = (const float*)d_in[5];
  const float* b_glob    = (const float*)d_in[6];
  const float* W_gv0     = (const float*)d_in[7];
  const float* b_gv0     = (const float*)d_in[8];
  const float* W_gv1     = (const float*)d_in[9];
  const float* b_gv1     = (const float*)d_in[10];
  const float* W_gq      = (const float*)d_in[11];
  const float* b_gq      = (const float*)d_in[12];
  const float* W_lq      = (const float*)d_in[13];
  const float* b_lq      = (const float*)d_in[14];
  const float* W_locgate = (const float*)d_in[15];
  const float* b_locgate = (const float*)d_in[16];
  const float* W_gate    = (const float*)d_in[17];
  const float* b_gate    = (const float*)d_in[18];
  float* out = (float*)d_out;

  float* ws = (float*)d_ws;
  float* party0   = ws;                    // 8192
  float* party1   = party0 + 8192;         // 8192
  float* tmp_glob = party1 + 8192;         // 256
  float* g1       = tmp_glob + 256;        // 256
  float* k_enc2   = g1 + 256;              // 131072
  float* cvec     = k_enc2 + 131072;       // 512
  float* gl2      = cvec + 512;            // 512
  float* q_glob   = gl2 + 512;             // 65536
  float* q_loc    = q_glob + 65536;        // 65536
  float* qk_r     = q_loc + 65536;         // 131072 (becomes exs after kcL)
  float* qnk_r    = qk_r + 131072;         // 131072
  float* evb      = qnk_r + 131072;        // 131072
  float* v2       = evb + 131072;          // 131072
  float* coef     = v2 + 131072;           // 131072
  unsigned short* mbf  = (unsigned short*)(coef + 131072); // 262144 u16
  unsigned short* ebf  = mbf + 262144;     // 131072 u16
  unsigned short* ecbf = ebf + 131072;     // 131072 u16
  unsigned short* wvbf = ecbf + 131072;    // 131072 u16

  kA2<<<32, 256, 0, stream>>>(q_enc, W_glob, W_gv0, party0, party1);
  kA3<<<1, 256, 0, stream>>>(party0, party1, b_glob, b_gv0, tmp_glob, g1);
  k23<<<768, 256, 0, stream>>>(k_enc, W_gv1, b_gv1, tmp_glob, g1, W_locgate,
                               k_enc2, cvec, gl2,
                               q_enc, W_gq, b_gq, W_lq, b_lq, q_glob, q_loc,
                               k_adj, mbf);
  kb_relk<<<32768, 256, 0, stream>>>(rel_k, q_glob, q_loc, qk_r, qnk_r);
  kcL<<<dim3(16, 16), 128, 0, stream>>>(q_glob, q_loc, k_enc2, cvec, qk_r, qnk_r,
                                        evb, ebf, ecbf);
  kcA2m<<<dim3(8, 16), 256, 0, stream>>>(ebf, ecbf, mbf, qk_r, gl2, b_locgate, wvbf, v2);
  kcC2m<<<dim3(8, 16), 256, 0, stream>>>(wvbf, mbf, evb, v2, coef);
  kDE<<<256, 512, 0, stream>>>(rel_v, k_enc2, qk_r, coef, q_enc, W_gate, b_gate, out);
}

// Round 5
// 102.009 us; speedup vs baseline: 3.3047x; 1.0635x over previous
//
#include <hip/hip_runtime.h>
#include <math.h>

#define QN 256
#define KN 512
#define DN 256
#define SCALE 0.0625f  // 1/sqrt(256)

typedef __attribute__((ext_vector_type(8))) short short8v;
typedef __attribute__((ext_vector_type(4))) float f32x4;

__device__ __forceinline__ float sigf(float x){ return 1.0f/(1.0f+expf(-x)); }

__device__ __forceinline__ unsigned short f2bf(float x){
  unsigned u = __float_as_uint(x);
  unsigned r = (u + 0x7FFFu + ((u >> 16) & 1u)) >> 16;
  return (unsigned short)r;
}

// load 8 bf16 from LDS: elems 0-3 at p[0..3], elems 4-7 at p[16..19] (two K-halves)
__device__ __forceinline__ short8v ld8(const unsigned short* p){
  ushort4 a = *(const ushort4*)p;
  ushort4 b = *(const ushort4*)(p + 16);
  short8v r;
  r[0]=(short)a.x; r[1]=(short)a.y; r[2]=(short)a.z; r[3]=(short)a.w;
  r[4]=(short)b.x; r[5]=(short)b.y; r[6]=(short)b.z; r[7]=(short)b.w;
  return r;
}

__device__ __forceinline__ float wave_red(float v){
  #pragma unroll
  for (int off = 32; off; off >>= 1) v += __shfl_down(v, off);
  return v;  // valid on lane 0
}

// kA2 (32 blocks x 256): block b: qmean for cols [8b,8b+8) + GEMV partials for both weights
__global__ void kA2(const float* __restrict__ q_enc,
                    const float* __restrict__ W_glob, const float* __restrict__ W_gv0,
                    float* __restrict__ party0, float* __restrict__ party1){
  __shared__ float sm[256][9];
  __shared__ float qm[8];
  int b = blockIdx.x, t = threadIdx.x;
  int j0 = b*8;
  float4 lo = *(const float4*)(q_enc + (size_t)t*DN + j0);
  float4 hi = *(const float4*)(q_enc + (size_t)t*DN + j0 + 4);
  sm[t][0]=lo.x; sm[t][1]=lo.y; sm[t][2]=lo.z; sm[t][3]=lo.w;
  sm[t][4]=hi.x; sm[t][5]=hi.y; sm[t][6]=hi.z; sm[t][7]=hi.w;
  __syncthreads();
  #pragma unroll
  for (int s = 128; s > 0; s >>= 1){
    if (t < s){
      #pragma unroll
      for (int j = 0; j < 8; ++j) sm[t][j] += sm[t+s][j];
    }
    __syncthreads();
  }
  if (t < 8) qm[t] = sm[0][t] * (1.0f/QN);
  __syncthreads();
  float a0 = 0.f, a1 = 0.f;
  #pragma unroll
  for (int j = 0; j < 8; ++j){
    float s = qm[j];
    a0 = fmaf(s, W_glob[(size_t)(j0+j)*DN + t], a0);
    a1 = fmaf(s, W_gv0[(size_t)(j0+j)*DN + t], a1);
  }
  party0[b*256 + t] = a0; party1[b*256 + t] = a1;
}

// kA3 (1 block): reduce 32 partials + bias -> tmp_glob, g1
__global__ void kA3(const float* __restrict__ party0, const float* __restrict__ party1,
                    const float* __restrict__ b_glob, const float* __restrict__ b_gv0,
                    float* __restrict__ tmp_glob, float* __restrict__ g1){
  int t = threadIdx.x;
  float a0 = b_glob[t], a1 = b_gv0[t];
  #pragma unroll
  for (int b = 0; b < 32; ++b){ a0 += party0[b*256 + t]; a1 += party1[b*256 + t]; }
  tmp_glob[t] = a0; g1[t] = a1;
}

// k23 (768 blocks): bid<512 -> k2 body (k=bid); else k3 body (q=bid-512). Plus mask->bf16 convert.
__global__ void k23(const float* __restrict__ k_enc,
                    const float* __restrict__ W_gv1, const float* __restrict__ b_gv1,
                    const float* __restrict__ tmp_glob, const float* __restrict__ g1,
                    const float* __restrict__ W_locgate,
                    float* __restrict__ k_enc2, float* __restrict__ cvec,
                    float* __restrict__ gl2,
                    const float* __restrict__ q_enc,
                    const float* __restrict__ W_gq, const float* __restrict__ b_gq,
                    const float* __restrict__ W_lq, const float* __restrict__ b_lq,
                    float* __restrict__ q_glob, float* __restrict__ q_loc,
                    const int* __restrict__ kadj, unsigned short* __restrict__ mbf){
  __shared__ float sh1[256];
  __shared__ float red8[8];
  int bid = blockIdx.x, t = threadIdx.x;
  int w = t >> 6, lane = t & 63;
  // fused mask convert: 65536 int4 chunks over 196608 threads
  int gid = bid*256 + t;
  if (gid < 65536){
    int4 v = ((const int4*)kadj)[gid];
    ushort4 o;
    o.x = v.x ? 0x3F80 : 0; o.y = v.y ? 0x3F80 : 0;
    o.z = v.z ? 0x3F80 : 0; o.w = v.w ? 0x3F80 : 0;
    ((ushort4*)mbf)[gid] = o;
  }
  if (bid < 512){
    int k = bid;
    float kv = k_enc[(size_t)k*DN + t];
    sh1[t] = kv;
    float part = wave_red(kv * tmp_glob[t]);
    if (lane == 0) red8[w] = part;
    __syncthreads();                       // covers sh1 + red8
    float dot = red8[0] + red8[1] + red8[2] + red8[3];
    float ks = sigf(dot * SCALE);
    float acc = b_gv1[t];
    #pragma unroll 8
    for (int j = 0; j < DN; ++j) acc = fmaf(sh1[j], W_gv1[(size_t)j*DN + t], acc);
    float v = (1.f - ks)*acc + ks*g1[t];
    k_enc2[(size_t)k*DN + t] = v;
    float pc = wave_red(v * W_locgate[t]);
    float pg = wave_red(v * W_locgate[DN + t]);
    __syncthreads();                       // all dot-reads done before red8 reuse
    if (lane == 0){ red8[w] = pc; red8[4 + w] = pg; }
    __syncthreads();
    if (t == 0) cvec[k] = red8[0] + red8[1] + red8[2] + red8[3];
    if (t == 1) gl2[k]  = red8[4] + red8[5] + red8[6] + red8[7];
  } else {
    int q = bid - 512;
    sh1[t] = q_enc[(size_t)q*DN + t];
    __syncthreads();
    float a = b_gq[t], b = b_lq[t];
    #pragma unroll 8
    for (int j = 0; j < DN; ++j){
      float s = sh1[j];
      a = fmaf(s, W_gq[(size_t)j*DN + t], a);
      b = fmaf(s, W_lq[(size_t)j*DN + t], b);
    }
    q_glob[(size_t)q*DN + t] = a; q_loc[(size_t)q*DN + t] = b;
  }
}

// kb2: one wave per (q,k). Full logits (rel dot + GEMM dot vs k_enc2) + tanh/exp epilogue.
// Emits exs (unnorm glob numerator), ev, ebf, ecbf. Replaces old kb_relk + kcL.
__global__ void kb2(const float* __restrict__ rel_k,
                    const float* __restrict__ q_glob, const float* __restrict__ q_loc,
                    const float* __restrict__ ke2, const float* __restrict__ cvec,
                    float* __restrict__ exs, float* __restrict__ ev,
                    unsigned short* __restrict__ ebf, unsigned short* __restrict__ ecbf){
  int w = blockIdx.x*4 + (threadIdx.x >> 6);
  int lane = threadIdx.x & 63;
  int q = w >> 9, k = w & 511;
  float4 x = ((const float4*)(rel_k + (size_t)(q*KN + k)*DN))[lane];
  float4 a = ((const float4*)(q_glob + (size_t)q*DN))[lane];
  float4 b = ((const float4*)(q_loc  + (size_t)q*DN))[lane];
  float4 c = ((const float4*)(ke2    + (size_t)k*DN))[lane];
  float p1 = x.x*a.x + x.y*a.y + x.z*a.z + x.w*a.w;
  float p2 = x.x*b.x + x.y*b.y + x.z*b.z + x.w*b.w;
  float p3 = c.x*a.x + c.y*a.y + c.z*a.z + c.w*a.w;
  float p4 = c.x*b.x + c.y*b.y + c.z*b.z + c.w*b.w;
  #pragma unroll
  for (int off = 32; off; off >>= 1){
    p1 += __shfl_down(p1, off); p2 += __shfl_down(p2, off);
    p3 += __shfl_down(p3, off); p4 += __shfl_down(p4, off);
  }
  if (lane == 0){
    size_t idx = (size_t)q*KN + k;
    exs[idx] = expf(tanhf((p1 + p3)*SCALE));
    float evv = expf(tanhf((p2 + p4)*SCALE));
    ev[idx] = evv;
    ebf[idx] = f2bf(evv);
    ecbf[idx] = f2bf(evv * cvec[k]);
  }
}

// kcA2m (grid (8,16), 256 thr): MFMA dual {e,ec}@M^T over j (K=512), tile 16q x 64i.
// Epilogue: lg = sig(an/as + gl2 + b); wv_bf = exs*lg/as; v2 = exs*(1-lg).
__global__ __launch_bounds__(256) void kcA2m(const unsigned short* __restrict__ ebf,
                                             const unsigned short* __restrict__ ecbf,
                                             const unsigned short* __restrict__ mbf,
                                             const float* __restrict__ exs,
                                             const float* __restrict__ gl2,
                                             const float* __restrict__ blg_p,
                                             unsigned short* __restrict__ wvbf,
                                             float* __restrict__ v2){
  __shared__ unsigned short Ae[16*520];
  __shared__ unsigned short Ac[16*520];
  __shared__ unsigned short Bm[64*520];
  int t = threadIdx.x;
  int i0 = blockIdx.x*64, q0 = blockIdx.y*16;
  #pragma unroll
  for (int it = 0; it < 4; ++it){
    int c = t + 256*it; int row = c >> 6, col = (c & 63)*8;
    *(uint4*)&Ae[row*520 + col] = *(const uint4*)&ebf[(size_t)(q0+row)*KN + col];
    *(uint4*)&Ac[row*520 + col] = *(const uint4*)&ecbf[(size_t)(q0+row)*KN + col];
  }
  #pragma unroll
  for (int it = 0; it < 16; ++it){
    int c = t + 256*it; int row = c >> 6, col = (c & 63)*8;
    *(uint4*)&Bm[row*520 + col] = *(const uint4*)&mbf[(size_t)(i0+row)*KN + col];
  }
  __syncthreads();
  int w = t >> 6, l = t & 63;
  int g16 = l >> 4, l16 = l & 15;
  f32x4 aS = {0.f,0.f,0.f,0.f}, aN = {0.f,0.f,0.f,0.f};
  const unsigned short* pe = &Ae[l16*520];
  const unsigned short* pc = &Ac[l16*520];
  const unsigned short* pb = &Bm[(16*w + l16)*520];
  #pragma unroll
  for (int kk = 0; kk < 16; ++kk){
    int k0 = kk*32 + 4*g16;
    short8v fa = ld8(pe + k0);
    short8v fc = ld8(pc + k0);
    short8v fb = ld8(pb + k0);
    aS = __builtin_amdgcn_mfma_f32_16x16x32_bf16(fa, fb, aS, 0, 0, 0);
    aN = __builtin_amdgcn_mfma_f32_16x16x32_bf16(fc, fb, aN, 0, 0, 0);
  }
  float blg = blg_p[0];
  int i = i0 + 16*w + l16;
  float gli = gl2[i];
  #pragma unroll
  for (int r = 0; r < 4; ++r){
    int q = q0 + 4*g16 + r;
    size_t idx = (size_t)q*KN + i;
    float s = aS[r], n = aN[r];
    float lgv = sigf(n/s + gli + blg);
    float ex = exs[idx];
    wvbf[idx] = f2bf(ex*lgv/s);
    v2[idx] = ex*(1.f - lgv);
  }
}

// kcC2m (grid (8,16), 256 thr): MFMA u = wv@M over i (K=512), tile 16q x 64j.
// Epilogue: coef = u*ev + v2.
__global__ __launch_bounds__(256) void kcC2m(const unsigned short* __restrict__ wvbf,
                                             const unsigned short* __restrict__ mbf,
                                             const float* __restrict__ ev,
                                             const float* __restrict__ v2,
                                             float* __restrict__ coef){
  __shared__ unsigned short Aw[16*520];
  __shared__ unsigned short Bm2[512*72];
  int t = threadIdx.x;
  int j0 = blockIdx.x*64, q0 = blockIdx.y*16;
  #pragma unroll
  for (int it = 0; it < 4; ++it){
    int c = t + 256*it; int row = c >> 6, col = (c & 63)*8;
    *(uint4*)&Aw[row*520 + col] = *(const uint4*)&wvbf[(size_t)(q0+row)*KN + col];
  }
  #pragma unroll
  for (int it = 0; it < 16; ++it){
    int c = t + 256*it; int row = c >> 3, col = (c & 7)*8;
    *(uint4*)&Bm2[row*72 + col] = *(const uint4*)&mbf[(size_t)row*KN + j0 + col];
  }
  __syncthreads();
  int w = t >> 6, l = t & 63;
  int g16 = l >> 4, l16 = l & 15;
  f32x4 aU = {0.f,0.f,0.f,0.f};
  const unsigned short* pa = &Aw[l16*520];
  int nn = 16*w + l16;
  #pragma unroll
  for (int kk = 0; kk < 16; ++kk){
    int k0 = kk*32 + 4*g16;
    short8v fa = ld8(pa + k0);
    short8v fb;
    #pragma unroll
    for (int e = 0; e < 4; ++e){
      fb[e]   = (short)Bm2[(k0+e)*72 + nn];
      fb[4+e] = (short)Bm2[(k0+16+e)*72 + nn];
    }
    aU = __builtin_amdgcn_mfma_f32_16x16x32_bf16(fa, fb, aU, 0, 0, 0);
  }
  int j = j0 + nn;
  #pragma unroll
  for (int r = 0; r < 4; ++r){
    int q = q0 + 4*g16 + r;
    size_t idx = (size_t)q*KN + j;
    coef[idx] = aU[r]*ev[idx] + v2[idx];
  }
}

// kDE (grid 256, 512 thr): invs from exs row; acc = Σ_k exs*rel_v + coef'*k_enc2; ×invs; gate -> out
__global__ __launch_bounds__(512) void kDE(const float* __restrict__ relv,
                                           const float* __restrict__ ke2,
                                           const float* __restrict__ exs,
                                           const float* __restrict__ coef,
                                           const float* __restrict__ q_enc,
                                           const float* __restrict__ W_gate,
                                           const float* __restrict__ b_gate,
                                           float* __restrict__ out){
  __shared__ float red[512];
  __shared__ float4 pacc[8][64];
  int q = blockIdx.x, t = threadIdx.x, w = t >> 6, lane = t & 63;
  red[t] = exs[(size_t)q*KN + t];
  __syncthreads();
  #pragma unroll
  for (int s = 256; s > 0; s >>= 1){
    if (t < s) red[t] += red[t+s];
    __syncthreads();
  }
  float invs = 1.0f / red[0];
  float4 acc = make_float4(0.f,0.f,0.f,0.f);
  int kbase = w*64;
  #pragma unroll 4
  for (int kk = 0; kk < 64; ++kk){
    int k = kbase + kk;
    float gk = exs[(size_t)q*KN + k];
    float ck = coef[(size_t)q*KN + k];
    float4 xv = ((const float4*)(relv + (size_t)(q*KN + k)*DN))[lane];
    float4 kv = ((const float4*)(ke2 + (size_t)k*DN))[lane];
    acc.x = fmaf(gk, xv.x, fmaf(ck, kv.x, acc.x));
    acc.y = fmaf(gk, xv.y, fmaf(ck, kv.y, acc.y));
    acc.z = fmaf(gk, xv.z, fmaf(ck, kv.z, acc.z));
    acc.w = fmaf(gk, xv.w, fmaf(ck, kv.w, acc.w));
  }
  pacc[w][lane] = acc;
  __syncthreads();
  if (t < 64){
    float4 r = pacc[0][t];
    #pragma unroll
    for (int w2 = 1; w2 < 8; ++w2){
      float4 p = pacc[w2][t];
      r.x += p.x; r.y += p.y; r.z += p.z; r.w += p.w;
    }
    r.x *= invs; r.y *= invs; r.z *= invs; r.w *= invs;
    float4 qe = ((const float4*)(q_enc + (size_t)q*DN))[t];
    float4 w1 = ((const float4*)(W_gate))[t];
    float4 w2v = ((const float4*)(W_gate + DN))[t];
    float pd = r.x*w1.x + r.y*w1.y + r.z*w1.z + r.w*w1.w
             + qe.x*w2v.x + qe.y*w2v.y + qe.z*w2v.z + qe.w*w2v.w;
    #pragma unroll
    for (int off = 32; off; off >>= 1) pd += __shfl_down(pd, off);
    float gate = sigf(__shfl(pd, 0) + b_gate[0]);
    float4 h;
    h.x = gate*r.x + (1.f-gate)*qe.x;
    h.y = gate*r.y + (1.f-gate)*qe.y;
    h.z = gate*r.z + (1.f-gate)*qe.z;
    h.w = gate*r.w + (1.f-gate)*qe.w;
    ((float4*)(out + (size_t)q*DN))[t] = h;
  }
}

extern "C" void kernel_launch(void* const* d_in, const int* in_sizes, int n_in,
                              void* d_out, int out_size, void* d_ws, size_t ws_size,
                              hipStream_t stream){
  const float* q_enc     = (const float*)d_in[0];
  const float* k_enc     = (const float*)d_in[1];
  const float* rel_k     = (const float*)d_in[2];
  const float* rel_v     = (const float*)d_in[3];
  const int*   k_adj     = (const int*)  d_in[4];
  const float* W_glob    = (const float*)d_in[5];
  const float* b_glob    = (const float*)d_in[6];
  const float* W_gv0     = (const float*)d_in[7];
  const float* b_gv0     = (const float*)d_in[8];
  const float* W_gv1     = (const float*)d_in[9];
  const float* b_gv1     = (const float*)d_in[10];
  const float* W_gq      = (const float*)d_in[11];
  const float* b_gq      = (const float*)d_in[12];
  const float* W_lq      = (const float*)d_in[13];
  const float* b_lq      = (const float*)d_in[14];
  const float* W_locgate = (const float*)d_in[15];
  const float* b_locgate = (const float*)d_in[16];
  const float* W_gate    = (const float*)d_in[17];
  const float* b_gate    = (const float*)d_in[18];
  float* out = (float*)d_out;

  float* ws = (float*)d_ws;
  float* party0   = ws;                    // 8192
  float* party1   = party0 + 8192;         // 8192
  float* tmp_glob = party1 + 8192;         // 256
  float* g1       = tmp_glob + 256;        // 256
  float* k_enc2   = g1 + 256;              // 131072
  float* cvec     = k_enc2 + 131072;       // 512
  float* gl2      = cvec + 512;            // 512
  float* q_glob   = gl2 + 512;             // 65536
  float* q_loc    = q_glob + 65536;        // 65536
  float* exs      = q_loc + 65536;         // 131072
  float* evb      = exs + 131072;          // 131072
  float* v2       = evb + 131072;          // 131072
  float* coef     = v2 + 131072;           // 131072
  unsigned short* mbf  = (unsigned short*)(coef + 131072); // 262144 u16
  unsigned short* ebf  = mbf + 262144;     // 131072 u16
  unsigned short* ecbf = ebf + 131072;     // 131072 u16
  unsigned short* wvbf = ecbf + 131072;    // 131072 u16

  kA2<<<32, 256, 0, stream>>>(q_enc, W_glob, W_gv0, party0, party1);
  kA3<<<1, 256, 0, stream>>>(party0, party1, b_glob, b_gv0, tmp_glob, g1);
  k23<<<768, 256, 0, stream>>>(k_enc, W_gv1, b_gv1, tmp_glob, g1, W_locgate,
                               k_enc2, cvec, gl2,
                               q_enc, W_gq, b_gq, W_lq, b_lq, q_glob, q_loc,
                               k_adj, mbf);
  kb2<<<32768, 256, 0, stream>>>(rel_k, q_glob, q_loc, k_enc2, cvec,
                                 exs, evb, ebf, ecbf);
  kcA2m<<<dim3(8, 16), 256, 0, stream>>>(ebf, ecbf, mbf, exs, gl2, b_locgate, wvbf, v2);
  kcC2m<<<dim3(8, 16), 256, 0, stream>>>(wvbf, mbf, evb, v2, coef);
  kDE<<<256, 512, 0, stream>>>(rel_v, k_enc2, exs, coef, q_enc, W_gate, b_gate, out);
}

// Round 7
// 91.382 us; speedup vs baseline: 3.6890x; 1.1163x over previous
//
#include <hip/hip_runtime.h>
#include <math.h>

#define QN 256
#define KN 512
#define DN 256
#define SCALE 0.0625f  // 1/sqrt(256)

typedef __attribute__((ext_vector_type(8))) short short8v;
typedef __attribute__((ext_vector_type(4))) float f32x4;

__device__ __forceinline__ float sigf(float x){ return 1.0f/(1.0f+expf(-x)); }

__device__ __forceinline__ unsigned short f2bf(float x){
  unsigned u = __float_as_uint(x);
  unsigned r = (u + 0x7FFFu + ((u >> 16) & 1u)) >> 16;
  return (unsigned short)r;
}

// load 8 bf16 from LDS: elems 0-3 at p[0..3], elems 4-7 at p[16..19] (two K-halves)
__device__ __forceinline__ short8v ld8(const unsigned short* p){
  ushort4 a = *(const ushort4*)p;
  ushort4 b = *(const ushort4*)(p + 16);
  short8v r;
  r[0]=(short)a.x; r[1]=(short)a.y; r[2]=(short)a.z; r[3]=(short)a.w;
  r[4]=(short)b.x; r[5]=(short)b.y; r[6]=(short)b.z; r[7]=(short)b.w;
  return r;
}

__device__ __forceinline__ float wave_red(float v){
  #pragma unroll
  for (int off = 32; off; off >>= 1) v += __shfl_down(v, off);
  return v;  // valid on lane 0
}

// kA2 (32 blocks x 256): block b: qmean for cols [8b,8b+8) + GEMV partials for both weights
__global__ void kA2(const float* __restrict__ q_enc,
                    const float* __restrict__ W_glob, const float* __restrict__ W_gv0,
                    float* __restrict__ party0, float* __restrict__ party1){
  __shared__ float sm[256][9];
  __shared__ float qm[8];
  int b = blockIdx.x, t = threadIdx.x;
  int j0 = b*8;
  float4 lo = *(const float4*)(q_enc + (size_t)t*DN + j0);
  float4 hi = *(const float4*)(q_enc + (size_t)t*DN + j0 + 4);
  sm[t][0]=lo.x; sm[t][1]=lo.y; sm[t][2]=lo.z; sm[t][3]=lo.w;
  sm[t][4]=hi.x; sm[t][5]=hi.y; sm[t][6]=hi.z; sm[t][7]=hi.w;
  __syncthreads();
  #pragma unroll
  for (int s = 128; s > 0; s >>= 1){
    if (t < s){
      #pragma unroll
      for (int j = 0; j < 8; ++j) sm[t][j] += sm[t+s][j];
    }
    __syncthreads();
  }
  if (t < 8) qm[t] = sm[0][t] * (1.0f/QN);
  __syncthreads();
  float a0 = 0.f, a1 = 0.f;
  #pragma unroll
  for (int j = 0; j < 8; ++j){
    float s = qm[j];
    a0 = fmaf(s, W_glob[(size_t)(j0+j)*DN + t], a0);
    a1 = fmaf(s, W_gv0[(size_t)(j0+j)*DN + t], a1);
  }
  party0[b*256 + t] = a0; party1[b*256 + t] = a1;
}

// k23 (768 blocks): bid<512 -> k2 body (k=bid, with inline kA3 re-reduce); else k3 body.
// Plus mask->bf16 convert fused across first 256 blocks.
__global__ void k23(const float* __restrict__ k_enc,
                    const float* __restrict__ W_gv1, const float* __restrict__ b_gv1,
                    const float* __restrict__ party0, const float* __restrict__ party1,
                    const float* __restrict__ b_glob, const float* __restrict__ b_gv0,
                    const float* __restrict__ W_locgate,
                    float* __restrict__ k_enc2, float* __restrict__ cvec,
                    float* __restrict__ gl2,
                    const float* __restrict__ q_enc,
                    const float* __restrict__ W_gq, const float* __restrict__ b_gq,
                    const float* __restrict__ W_lq, const float* __restrict__ b_lq,
                    float* __restrict__ q_glob, float* __restrict__ q_loc,
                    const int* __restrict__ kadj, unsigned short* __restrict__ mbf){
  __shared__ float sh1[256];
  __shared__ float red8[8];
  int bid = blockIdx.x, t = threadIdx.x;
  int w = t >> 6, lane = t & 63;
  // fused mask convert: 65536 int4 chunks over blocks 0..255
  int gid = bid*256 + t;
  if (gid < 65536){
    int4 v = ((const int4*)kadj)[gid];
    ushort4 o;
    o.x = v.x ? 0x3F80 : 0; o.y = v.y ? 0x3F80 : 0;
    o.z = v.z ? 0x3F80 : 0; o.w = v.w ? 0x3F80 : 0;
    ((ushort4*)mbf)[gid] = o;
  }
  if (bid < 512){
    int k = bid;
    // inline kA3: reduce 32 GEMV partials + bias (L2-hot, coalesced)
    float tg = b_glob[t], g1v = b_gv0[t];
    #pragma unroll 8
    for (int b2 = 0; b2 < 32; ++b2){
      tg  += party0[b2*256 + t];
      g1v += party1[b2*256 + t];
    }
    float kv = k_enc[(size_t)k*DN + t];
    sh1[t] = kv;
    float part = wave_red(kv * tg);
    if (lane == 0) red8[w] = part;
    __syncthreads();                       // covers sh1 + red8
    float dot = red8[0] + red8[1] + red8[2] + red8[3];
    float ks = sigf(dot * SCALE);
    float acc = b_gv1[t];
    #pragma unroll 8
    for (int j = 0; j < DN; ++j) acc = fmaf(sh1[j], W_gv1[(size_t)j*DN + t], acc);
    float v = (1.f - ks)*acc + ks*g1v;
    k_enc2[(size_t)k*DN + t] = v;
    float pc = wave_red(v * W_locgate[t]);
    float pg = wave_red(v * W_locgate[DN + t]);
    __syncthreads();                       // all dot-reads done before red8 reuse
    if (lane == 0){ red8[w] = pc; red8[4 + w] = pg; }
    __syncthreads();
    if (t == 0) cvec[k] = red8[0] + red8[1] + red8[2] + red8[3];
    if (t == 1) gl2[k]  = red8[4] + red8[5] + red8[6] + red8[7];
  } else {
    int q = bid - 512;
    sh1[t] = q_enc[(size_t)q*DN + t];
    __syncthreads();
    float a = b_gq[t], b = b_lq[t];
    #pragma unroll 8
    for (int j = 0; j < DN; ++j){
      float s = sh1[j];
      a = fmaf(s, W_gq[(size_t)j*DN + t], a);
      b = fmaf(s, W_lq[(size_t)j*DN + t], b);
    }
    q_glob[(size_t)q*DN + t] = a; q_loc[(size_t)q*DN + t] = b;
  }
}

// kb2 (8192 blocks x 256): 16 lanes per (q,k) -> 4 k per wave, 16 k per block.
// Full logits (rel dot + GEMM dot vs k_enc2) + tanh/exp epilogue.
__global__ void kb2(const float* __restrict__ rel_k,
                    const float* __restrict__ q_glob, const float* __restrict__ q_loc,
                    const float* __restrict__ ke2, const float* __restrict__ cvec,
                    float* __restrict__ exs, float* __restrict__ ev,
                    unsigned short* __restrict__ ebf, unsigned short* __restrict__ ecbf){
  int t = threadIdx.x;
  int wv = t >> 6, lane = t & 63;
  int g = lane >> 4, l16 = lane & 15;
  int b = blockIdx.x;
  int q = b >> 5;
  int k = (b & 31)*16 + wv*4 + g;
  float p1 = 0.f, p2 = 0.f, p3 = 0.f, p4 = 0.f;
  #pragma unroll
  for (int it = 0; it < 4; ++it){
    int d = it*64 + l16*4;
    f32x4 x  = __builtin_nontemporal_load((const f32x4*)(rel_k + ((size_t)q*KN + k)*DN + d));
    float4 a  = *(const float4*)(q_glob + (size_t)q*DN + d);
    float4 bb = *(const float4*)(q_loc  + (size_t)q*DN + d);
    float4 c  = *(const float4*)(ke2    + (size_t)k*DN + d);
    p1 += x[0]*a.x + x[1]*a.y + x[2]*a.z + x[3]*a.w;
    p2 += x[0]*bb.x + x[1]*bb.y + x[2]*bb.z + x[3]*bb.w;
    p3 += c.x*a.x + c.y*a.y + c.z*a.z + c.w*a.w;
    p4 += c.x*bb.x + c.y*bb.y + c.z*bb.z + c.w*bb.w;
  }
  #pragma unroll
  for (int off = 8; off; off >>= 1){
    p1 += __shfl_down(p1, off); p2 += __shfl_down(p2, off);
    p3 += __shfl_down(p3, off); p4 += __shfl_down(p4, off);
  }
  if (l16 == 0){
    size_t idx = (size_t)q*KN + k;
    exs[idx] = expf(tanhf((p1 + p3)*SCALE));
    float evv = expf(tanhf((p2 + p4)*SCALE));
    ev[idx] = evv;
    ebf[idx] = f2bf(evv);
    ecbf[idx] = f2bf(evv * cvec[k]);
  }
}

// kcA2m (grid (8,16), 256 thr): MFMA dual {e,ec}@M^T over j (K=512), tile 16q x 64i.
// Epilogue: lg = sig(an/as + gl2 + b); wv_bf = exs*lg/as; v2 = exs*(1-lg).
__global__ __launch_bounds__(256) void kcA2m(const unsigned short* __restrict__ ebf,
                                             const unsigned short* __restrict__ ecbf,
                                             const unsigned short* __restrict__ mbf,
                                             const float* __restrict__ exs,
                                             const float* __restrict__ gl2,
                                             const float* __restrict__ blg_p,
                                             unsigned short* __restrict__ wvbf,
                                             float* __restrict__ v2){
  __shared__ unsigned short Ae[16*520];
  __shared__ unsigned short Ac[16*520];
  __shared__ unsigned short Bm[64*520];
  int t = threadIdx.x;
  int i0 = blockIdx.x*64, q0 = blockIdx.y*16;
  #pragma unroll
  for (int it = 0; it < 4; ++it){
    int c = t + 256*it; int row = c >> 6, col = (c & 63)*8;
    *(uint4*)&Ae[row*520 + col] = *(const uint4*)&ebf[(size_t)(q0+row)*KN + col];
    *(uint4*)&Ac[row*520 + col] = *(const uint4*)&ecbf[(size_t)(q0+row)*KN + col];
  }
  #pragma unroll
  for (int it = 0; it < 16; ++it){
    int c = t + 256*it; int row = c >> 6, col = (c & 63)*8;
    *(uint4*)&Bm[row*520 + col] = *(const uint4*)&mbf[(size_t)(i0+row)*KN + col];
  }
  __syncthreads();
  int w = t >> 6, l = t & 63;
  int g16 = l >> 4, l16 = l & 15;
  f32x4 aS = {0.f,0.f,0.f,0.f}, aN = {0.f,0.f,0.f,0.f};
  const unsigned short* pe = &Ae[l16*520];
  const unsigned short* pc = &Ac[l16*520];
  const unsigned short* pb = &Bm[(16*w + l16)*520];
  #pragma unroll
  for (int kk = 0; kk < 16; ++kk){
    int k0 = kk*32 + 4*g16;
    short8v fa = ld8(pe + k0);
    short8v fc = ld8(pc + k0);
    short8v fb = ld8(pb + k0);
    aS = __builtin_amdgcn_mfma_f32_16x16x32_bf16(fa, fb, aS, 0, 0, 0);
    aN = __builtin_amdgcn_mfma_f32_16x16x32_bf16(fc, fb, aN, 0, 0, 0);
  }
  float blg = blg_p[0];
  int i = i0 + 16*w + l16;
  float gli = gl2[i];
  #pragma unroll
  for (int r = 0; r < 4; ++r){
    int q = q0 + 4*g16 + r;
    size_t idx = (size_t)q*KN + i;
    float s = aS[r], n = aN[r];
    float lgv = sigf(n/s + gli + blg);
    float ex = exs[idx];
    wvbf[idx] = f2bf(ex*lgv/s);
    v2[idx] = ex*(1.f - lgv);
  }
}

// kcC2m (grid (8,16), 256 thr): MFMA u = wv@M over i (K=512), tile 16q x 64j.
// Epilogue: coef = u*ev + v2.
__global__ __launch_bounds__(256) void kcC2m(const unsigned short* __restrict__ wvbf,
                                             const unsigned short* __restrict__ mbf,
                                             const float* __restrict__ ev,
                                             const float* __restrict__ v2,
                                             float* __restrict__ coef){
  __shared__ unsigned short Aw[16*520];
  __shared__ unsigned short Bm2[512*72];
  int t = threadIdx.x;
  int j0 = blockIdx.x*64, q0 = blockIdx.y*16;
  #pragma unroll
  for (int it = 0; it < 4; ++it){
    int c = t + 256*it; int row = c >> 6, col = (c & 63)*8;
    *(uint4*)&Aw[row*520 + col] = *(const uint4*)&wvbf[(size_t)(q0+row)*KN + col];
  }
  #pragma unroll
  for (int it = 0; it < 16; ++it){
    int c = t + 256*it; int row = c >> 3, col = (c & 7)*8;
    *(uint4*)&Bm2[row*72 + col] = *(const uint4*)&mbf[(size_t)row*KN + j0 + col];
  }
  __syncthreads();
  int w = t >> 6, l = t & 63;
  int g16 = l >> 4, l16 = l & 15;
  f32x4 aU = {0.f,0.f,0.f,0.f};
  const unsigned short* pa = &Aw[l16*520];
  int nn = 16*w + l16;
  #pragma unroll
  for (int kk = 0; kk < 16; ++kk){
    int k0 = kk*32 + 4*g16;
    short8v fa = ld8(pa + k0);
    short8v fb;
    #pragma unroll
    for (int e = 0; e < 4; ++e){
      fb[e]   = (short)Bm2[(k0+e)*72 + nn];
      fb[4+e] = (short)Bm2[(k0+16+e)*72 + nn];
    }
    aU = __builtin_amdgcn_mfma_f32_16x16x32_bf16(fa, fb, aU, 0, 0, 0);
  }
  int j = j0 + nn;
  #pragma unroll
  for (int r = 0; r < 4; ++r){
    int q = q0 + 4*g16 + r;
    size_t idx = (size_t)q*KN + j;
    coef[idx] = aU[r]*ev[idx] + v2[idx];
  }
}

// kDE (grid 256, 512 thr): invs from exs row; acc = Σ_k exs*rel_v + coef'*k_enc2; ×invs; gate -> out
__global__ __launch_bounds__(512) void kDE(const float* __restrict__ relv,
                                           const float* __restrict__ ke2,
                                           const float* __restrict__ exs,
                                           const float* __restrict__ coef,
                                           const float* __restrict__ q_enc,
                                           const float* __restrict__ W_gate,
                                           const float* __restrict__ b_gate,
                                           float* __restrict__ out){
  __shared__ float red[512];
  __shared__ float4 pacc[8][64];
  int q = blockIdx.x, t = threadIdx.x, w = t >> 6, lane = t & 63;
  red[t] = exs[(size_t)q*KN + t];
  __syncthreads();
  #pragma unroll
  for (int s = 256; s > 0; s >>= 1){
    if (t < s) red[t] += red[t+s];
    __syncthreads();
  }
  float invs = 1.0f / red[0];
  float4 acc = make_float4(0.f,0.f,0.f,0.f);
  int kbase = w*64;
  #pragma unroll 8
  for (int kk = 0; kk < 64; ++kk){
    int k = kbase + kk;
    float gk = exs[(size_t)q*KN + k];
    float ck = coef[(size_t)q*KN + k];
    f32x4 xv = __builtin_nontemporal_load((const f32x4*)(relv + ((size_t)q*KN + k)*DN) + lane);
    float4 kv = ((const float4*)(ke2 + (size_t)k*DN))[lane];
    acc.x = fmaf(gk, xv[0], fmaf(ck, kv.x, acc.x));
    acc.y = fmaf(gk, xv[1], fmaf(ck, kv.y, acc.y));
    acc.z = fmaf(gk, xv[2], fmaf(ck, kv.z, acc.z));
    acc.w = fmaf(gk, xv[3], fmaf(ck, kv.w, acc.w));
  }
  pacc[w][lane] = acc;
  __syncthreads();
  if (t < 64){
    float4 r = pacc[0][t];
    #pragma unroll
    for (int w2 = 1; w2 < 8; ++w2){
      float4 p = pacc[w2][t];
      r.x += p.x; r.y += p.y; r.z += p.z; r.w += p.w;
    }
    r.x *= invs; r.y *= invs; r.z *= invs; r.w *= invs;
    float4 qe = ((const float4*)(q_enc + (size_t)q*DN))[t];
    float4 w1 = ((const float4*)(W_gate))[t];
    float4 w2v = ((const float4*)(W_gate + DN))[t];
    float pd = r.x*w1.x + r.y*w1.y + r.z*w1.z + r.w*w1.w
             + qe.x*w2v.x + qe.y*w2v.y + qe.z*w2v.z + qe.w*w2v.w;
    #pragma unroll
    for (int off = 32; off; off >>= 1) pd += __shfl_down(pd, off);
    float gate = sigf(__shfl(pd, 0) + b_gate[0]);
    float4 h;
    h.x = gate*r.x + (1.f-gate)*qe.x;
    h.y = gate*r.y + (1.f-gate)*qe.y;
    h.z = gate*r.z + (1.f-gate)*qe.z;
    h.w = gate*r.w + (1.f-gate)*qe.w;
    ((float4*)(out + (size_t)q*DN))[t] = h;
  }
}

extern "C" void kernel_launch(void* const* d_in, const int* in_sizes, int n_in,
                              void* d_out, int out_size, void* d_ws, size_t ws_size,
                              hipStream_t stream){
  const float* q_enc     = (const float*)d_in[0];
  const float* k_enc     = (const float*)d_in[1];
  const float* rel_k     = (const float*)d_in[2];
  const float* rel_v     = (const float*)d_in[3];
  const int*   k_adj     = (const int*)  d_in[4];
  const float* W_glob    = (const float*)d_in[5];
  const float* b_glob    = (const float*)d_in[6];
  const float* W_gv0     = (const float*)d_in[7];
  const float* b_gv0     = (const float*)d_in[8];
  const float* W_gv1     = (const float*)d_in[9];
  const float* b_gv1     = (const float*)d_in[10];
  const float* W_gq      = (const float*)d_in[11];
  const float* b_gq      = (const float*)d_in[12];
  const float* W_lq      = (const float*)d_in[13];
  const float* b_lq      = (const float*)d_in[14];
  const float* W_locgate = (const float*)d_in[15];
  const float* b_locgate = (const float*)d_in[16];
  const float* W_gate    = (const float*)d_in[17];
  const float* b_gate    = (const float*)d_in[18];
  float* out = (float*)d_out;

  float* ws = (float*)d_ws;
  float* party0   = ws;                    // 8192
  float* party1   = party0 + 8192;         // 8192
  float* k_enc2   = party1 + 8192;         // 131072
  float* cvec     = k_enc2 + 131072;       // 512
  float* gl2      = cvec + 512;            // 512
  float* q_glob   = gl2 + 512;             // 65536
  float* q_loc    = q_glob + 65536;        // 65536
  float* exs      = q_loc + 65536;         // 131072
  float* evb      = exs + 131072;          // 131072
  float* v2       = evb + 131072;          // 131072
  float* coef     = v2 + 131072;           // 131072
  unsigned short* mbf  = (unsigned short*)(coef + 131072); // 262144 u16
  unsigned short* ebf  = mbf + 262144;     // 131072 u16
  unsigned short* ecbf = ebf + 131072;     // 131072 u16
  unsigned short* wvbf = ecbf + 131072;    // 131072 u16

  kA2<<<32, 256, 0, stream>>>(q_enc, W_glob, W_gv0, party0, party1);
  k23<<<768, 256, 0, stream>>>(k_enc, W_gv1, b_gv1, party0, party1, b_glob, b_gv0,
                               W_locgate, k_enc2, cvec, gl2,
                               q_enc, W_gq, b_gq, W_lq, b_lq, q_glob, q_loc,
                               k_adj, mbf);
  kb2<<<8192, 256, 0, stream>>>(rel_k, q_glob, q_loc, k_enc2, cvec,
                                exs, evb, ebf, ecbf);
  kcA2m<<<dim3(8, 16), 256, 0, stream>>>(ebf, ecbf, mbf, exs, gl2, b_locgate, wvbf, v2);
  kcC2m<<<dim3(8, 16), 256, 0, stream>>>(wvbf, mbf, evb, v2, coef);
  kDE<<<256, 512, 0, stream>>>(rel_v, k_enc2, exs, coef, q_enc, W_gate, b_gate, out);
}